// Round 8
// baseline (753.815 us; speedup 1.0000x reference)
//
#include <hip/hip_runtime.h>

#define EPS_BN 1e-5f

constexpr int NN   = 20000;       // nodes
constexpr int NE   = 320000;      // edges
constexpr int NTOT = NE + NN;     // edges + self loops
constexpr int NG   = 512;         // graphs
constexpr int MPAD = 20480;       // 160 * 128 rows
constexpr int NBLK = 79;          // ceil(NN/256)

typedef _Float16 half8  __attribute__((ext_vector_type(8)));
typedef _Float16 half2v __attribute__((ext_vector_type(2)));
typedef float floatx4   __attribute__((ext_vector_type(4)));

// ------------------------------------------------------------------
// Graph preprocessing
// ------------------------------------------------------------------
__global__ void k_deg(const int* __restrict__ col, int* __restrict__ deg,
                      const int* __restrict__ batch, int* __restrict__ gcnt) {
  int e = blockIdx.x * blockDim.x + threadIdx.x;
  if (e >= NTOT) return;
  int c = (e < NE) ? col[e] : (e - NE);
  atomicAdd(&deg[c], 1);
  if (e < NN) atomicAdd(&gcnt[batch[e]], 1);
}

// phase 1: per-block sums of deg + dinv
__global__ __launch_bounds__(256) void k_pre1(const int* __restrict__ deg,
                                              float* __restrict__ dinvv,
                                              int* __restrict__ psum) {
  __shared__ int ws[4];
  int t = threadIdx.x, lane = t & 63, wv = t >> 6;
  int idx = blockIdx.x * 256 + t;
  int d = (idx < NN) ? deg[idx] : 0;
  if (idx < NN) dinvv[idx] = rsqrtf((float)d);
  int s = d;
  for (int o = 1; o < 64; o <<= 1) { int u = __shfl_up(s, o, 64); if (lane >= o) s += u; }
  if (lane == 63) ws[wv] = s;
  __syncthreads();
  if (t == 0) psum[blockIdx.x] = ws[0] + ws[1] + ws[2] + ws[3];
}

// phase 2: scan the NBLK partials + scan gcnt (512) in one small block
__global__ __launch_bounds__(256) void k_pre2(const int* __restrict__ psum,
                                              int* __restrict__ pbase,
                                              const int* __restrict__ gcnt,
                                              int* __restrict__ goff) {
  __shared__ int ws[8];
  int t = threadIdx.x, lane = t & 63, wv = t >> 6;
  // part 1: psum[0..NBLK-1]
  int v = (t < NBLK) ? psum[t] : 0;
  int inc = v;
  for (int o = 1; o < 64; o <<= 1) { int u = __shfl_up(inc, o, 64); if (lane >= o) inc += u; }
  if (lane == 63) ws[wv] = inc;
  __syncthreads();
  int base = 0;
  for (int w = 0; w < wv; ++w) base += ws[w];
  int excl = base + inc - v;
  if (t < NBLK) pbase[t] = excl;
  if (t == NBLK - 1) pbase[NBLK] = excl + v;
  __syncthreads();
  // part 2: gcnt scan (512, 2 per thread)
  int a0 = gcnt[2 * t], a1 = gcnt[2 * t + 1];
  int p = a0 + a1;
  int incp = p;
  for (int o = 1; o < 64; o <<= 1) { int u = __shfl_up(incp, o, 64); if (lane >= o) incp += u; }
  if (lane == 63) ws[4 + wv] = incp;
  __syncthreads();
  int gb = 0;
  for (int w = 0; w < wv; ++w) gb += ws[4 + w];
  int exclp = gb + incp - p;
  goff[2 * t]     = exclp;
  goff[2 * t + 1] = exclp + a0;
  if (t == 255) goff[NG] = exclp + p;
}

// phase 3: emit indptr/cursor
__global__ __launch_bounds__(256) void k_pre3(const int* __restrict__ deg,
                                              const int* __restrict__ pbase,
                                              int* __restrict__ indptr,
                                              int* __restrict__ cursor) {
  __shared__ int ws[4];
  int t = threadIdx.x, lane = t & 63, wv = t >> 6;
  int idx = blockIdx.x * 256 + t;
  int d = (idx < NN) ? deg[idx] : 0;
  int inc = d;
  for (int o = 1; o < 64; o <<= 1) { int u = __shfl_up(inc, o, 64); if (lane >= o) inc += u; }
  if (lane == 63) ws[wv] = inc;
  __syncthreads();
  int base = pbase[blockIdx.x];
  for (int w = 0; w < wv; ++w) base += ws[w];
  int excl = base + inc - d;
  if (idx < NN) { indptr[idx] = excl; cursor[idx] = excl; }
  if (idx == NN - 1) indptr[NN] = excl + d;
}

// CSR fill with packed {src, w_bits} meta + rowsum
__global__ void k_fill(const int* __restrict__ row, const int* __restrict__ col,
                       const float* __restrict__ dinv, int* __restrict__ cursor,
                       int2* __restrict__ csw, float* __restrict__ rsum) {
  int e = blockIdx.x * blockDim.x + threadIdx.x;
  if (e >= NTOT) return;
  int r, c;
  if (e < NE) { r = row[e]; c = col[e]; } else { r = c = e - NE; }
  float wv = dinv[r] * dinv[c];
  int pos = atomicAdd(&cursor[c], 1);
  int2 m; m.x = r; m.y = __builtin_bit_cast(int, wv);
  csw[pos] = m;
  atomicAdd(&rsum[c], wv);
}

// ------------------------------------------------------------------
// Weight transposes (W1 pad 29->32, W4, W5) in one kernel
// ------------------------------------------------------------------
__global__ void k_wconv3(const float* __restrict__ W0, const float* __restrict__ W3,
                         const float* __restrict__ W4,
                         _Float16* __restrict__ T0, _Float16* __restrict__ T3,
                         _Float16* __restrict__ T4) {
  int idx = blockIdx.x * blockDim.x + threadIdx.x;
  if (idx < 32768) {                       // W1: K=29 (pad 32), N=1024
    int n = idx >> 5, k = idx & 31;
    T0[idx] = (_Float16)((k < 29) ? W0[(size_t)k * 1024 + n] : 0.f);
  } else if (idx < 32768 + 131072) {       // W4: K=256, N=512
    int j = idx - 32768;
    int n = j >> 8, k = j & 255;
    T3[j] = (_Float16)W3[(size_t)k * 512 + n];
  } else if (idx < 32768 + 131072 + 524288) { // W5: K=512, N=1024
    int j = idx - 163840;
    int n = j >> 9, k = j & 511;
    T4[j] = (_Float16)W4[(size_t)k * 1024 + n];
  }
}

// W' = diag(sc) W transposed to [N,K] fp16; c[n] = sum_k sh_k W[k,n]
__global__ __launch_bounds__(256) void k_wfold(const float* __restrict__ W, int K, int N,
                                               const float* __restrict__ sums,
                                               const float* __restrict__ gamma,
                                               const float* __restrict__ beta,
                                               _Float16* __restrict__ T,
                                               float* __restrict__ c) {
  __shared__ float red[256];
  int n = blockIdx.x, tid = threadIdx.x;
  const float inv_n = 1.f / NN;
  float csum = 0.f;
  for (int k = tid; k < K; k += 256) {
    float mean = sums[k] * inv_n;
    float var  = sums[K + k] * inv_n - mean * mean;
    float sc   = gamma[k] * rsqrtf(var + EPS_BN);
    float sh   = beta[k] - mean * sc;
    float wv   = W[(size_t)k * N + n];
    T[(size_t)n * K + k] = (_Float16)(sc * wv);
    csum += sh * wv;
  }
  red[tid] = csum;
  __syncthreads();
  for (int o = 128; o > 0; o >>= 1) {
    if (tid < o) red[tid] += red[tid + o];
    __syncthreads();
  }
  if (tid == 0) c[n] = red[0];
}

// ------------------------------------------------------------------
// L1 aggregation: fp32 x (F=29) -> fp16 out (stride 32)
// ------------------------------------------------------------------
#define AGG_T  128
#define AGG_CH 128
__global__ __launch_bounds__(AGG_T) void k_agg29(
    const float* __restrict__ X,
    const int* __restrict__ indptr, const int2* __restrict__ csw,
    _Float16* __restrict__ Y) {
  __shared__ int   s_src[AGG_CH];
  __shared__ float s_w[AGG_CH];
  int node = blockIdx.x;
  int tid  = threadIdx.x;
  int beg = indptr[node], end = indptr[node + 1];
  float acc = 0.f;
  for (int e0 = beg; e0 < end; e0 += AGG_CH) {
    int c = min(AGG_CH, end - e0);
    if (tid < c) {
      int2 m = csw[e0 + tid];
      s_src[tid] = m.x;
      s_w[tid]   = __builtin_bit_cast(float, m.y);
    }
    __syncthreads();
    for (int j = 0; j < c; ++j) {
      if (tid < 29) acc += s_w[j] * X[(size_t)s_src[j] * 29 + tid];
    }
    __syncthreads();
  }
  if (tid < 32) Y[(size_t)node * 32 + tid] = (tid < 29) ? (_Float16)acc : (_Float16)0.f;
}

// ------------------------------------------------------------------
// Whole-row fp16 gather aggregation, wave-per-node (4 nodes/block).
// Unroll-8 for memory parallelism.
// MODE 0: out = relu(acc + s*p0[f] + p1[f])
// MODE 1: out = sc[f]*acc + s*sh[f]  (BN from sums p0, gamma p1, beta p2)
// ------------------------------------------------------------------
template<int VEC, int MODE>
__global__ __launch_bounds__(256) void k_aggv(
    const _Float16* __restrict__ X, _Float16* __restrict__ Y,
    const int* __restrict__ indptr, const int2* __restrict__ csw,
    const float* __restrict__ rowsum,
    const float* __restrict__ p0, const float* __restrict__ p1,
    const float* __restrict__ p2)
{
  constexpr int F = 64 * VEC;
  int wave = threadIdx.x >> 6;
  int lane = threadIdx.x & 63;
  int node = blockIdx.x * 4 + wave;
  int beg = indptr[node], end = indptr[node + 1];
  float acc[VEC];
  #pragma unroll
  for (int i = 0; i < VEC; ++i) acc[i] = 0.f;
  const unsigned* Xl = (const unsigned*)X + lane * (VEC / 2);

  auto body = [&](int e) {
    int2 m = csw[e];
    float we = __builtin_bit_cast(float, m.y);
    const unsigned* xr = Xl + (size_t)m.x * (F / 2);
    unsigned uu[VEC / 2];
    if constexpr (VEC == 8) {
      uint4 d = *(const uint4*)xr;
      uu[0] = d.x; uu[1] = d.y; uu[2] = d.z; uu[3] = d.w;
    } else {
      uint2 d = *(const uint2*)xr;
      uu[0] = d.x; uu[1] = d.y;
    }
    #pragma unroll
    for (int i = 0; i < VEC / 2; ++i) {
      half2v h = __builtin_bit_cast(half2v, uu[i]);
      acc[2 * i]     = fmaf(we, (float)h[0], acc[2 * i]);
      acc[2 * i + 1] = fmaf(we, (float)h[1], acc[2 * i + 1]);
    }
  };
  int e = beg;
  for (; e + 8 <= end; e += 8) {
    body(e); body(e + 1); body(e + 2); body(e + 3);
    body(e + 4); body(e + 5); body(e + 6); body(e + 7);
  }
  for (; e < end; ++e) body(e);

  float s_n = rowsum[node];
  size_t ob = (size_t)node * F + lane * VEC;
  _Float16 outv[VEC];
  #pragma unroll
  for (int i = 0; i < VEC; ++i) {
    int f = lane * VEC + i;
    float v;
    if constexpr (MODE == 0) {
      v = fmaxf(acc[i] + s_n * p0[f] + p1[f], 0.f);
    } else {
      const float inv_n = 1.f / NN;
      float mean = p0[f] * inv_n;
      float var  = p0[F + f] * inv_n - mean * mean;
      float sc   = p1[f] * rsqrtf(var + EPS_BN);
      float sh   = p2[f] - mean * sc;
      v = sc * acc[i] + s_n * sh;
    }
    outv[i] = (_Float16)v;
  }
  if constexpr (VEC == 8) *(uint4*)(Y + ob) = *(const uint4*)outv;
  else                    *(uint2*)(Y + ob) = *(const uint2*)outv;
}

// ------------------------------------------------------------------
// LDS-free fp16 MFMA GEMM: both operands are L2-resident, so fragments
// are loaded straight from global into registers (no K-loop LDS, no
// K-loop barriers). 128x128 block, 4 waves 2x2, wave 64x64 (4x4 frags).
// LDS used only for the coalesced fp16 C epilogue + stats reduction.
// A: [MPAD,K] fp16. B^T: [N,K] fp16. Out fp16 Ch (+bias/relu/BN-stats).
// ------------------------------------------------------------------
template<int K>
__global__ __launch_bounds__(256) void k_gemmg(
    const _Float16* __restrict__ A, const _Float16* __restrict__ B,
    const float* __restrict__ bias,
    _Float16* __restrict__ Ch,
    float* __restrict__ stats,
    int N, int do_relu, int nbx)
{
  __shared__ __align__(16) _Float16 cs[128 * 136];
  __shared__ float sred[256];

  const int tid  = threadIdx.x;
  const int wave = tid >> 6;
  const int lane = tid & 63;

  int lin = blockIdx.x;
  int xcd = lin & 7, seq = lin >> 3;
  int bx = seq % nbx, grp = seq / nbx;
  int by = xcd + 8 * grp;            // 0..159
  const int row0 = by * 128;
  const int col0 = bx * 128;

  const int q  = lane >> 4;
  const int mm = lane & 15;
  const int wm = wave >> 1;
  const int wn = wave & 1;

  sred[tid] = 0.f;

  const _Float16* pa[4];
  const _Float16* pb[4];
  #pragma unroll
  for (int i = 0; i < 4; ++i)
    pa[i] = A + (size_t)(row0 + wm * 64 + i * 16 + mm) * K + q * 8;
  #pragma unroll
  for (int j = 0; j < 4; ++j)
    pb[j] = B + (size_t)(col0 + wn * 64 + j * 16 + mm) * K + q * 8;

  floatx4 acc[4][4];
  #pragma unroll
  for (int i = 0; i < 4; ++i)
    #pragma unroll
    for (int j = 0; j < 4; ++j) acc[i][j] = floatx4{0.f, 0.f, 0.f, 0.f};

  #pragma unroll 2
  for (int k0 = 0; k0 < K; k0 += 32) {
    half8 av[4], bv[4];
    #pragma unroll
    for (int i = 0; i < 4; ++i) { av[i] = *(const half8*)pa[i]; pa[i] += 32; }
    #pragma unroll
    for (int j = 0; j < 4; ++j) { bv[j] = *(const half8*)pb[j]; pb[j] += 32; }
    #pragma unroll
    for (int j = 0; j < 4; ++j)
      #pragma unroll
      for (int i = 0; i < 4; ++i)
        acc[i][j] = __builtin_amdgcn_mfma_f32_16x16x32_f16(av[i], bv[j], acc[i][j], 0, 0, 0);
  }

  // epilogue: fragments -> LDS tile (+stats), then coalesced stores
  float sloc[4]  = {0.f, 0.f, 0.f, 0.f};
  float s2loc[4] = {0.f, 0.f, 0.f, 0.f};
  #pragma unroll
  for (int j = 0; j < 4; ++j) {
    int cl = wn * 64 + j * 16 + mm;
    float bv = bias ? bias[col0 + cl] : 0.f;
    #pragma unroll
    for (int i = 0; i < 4; ++i) {
      #pragma unroll
      for (int r = 0; r < 4; ++r) {
        int rl = wm * 64 + i * 16 + q * 4 + r;
        float v = acc[i][j][r] + bv;
        if (do_relu) v = fmaxf(v, 0.f);
        cs[rl * 136 + cl] = (_Float16)v;
        if (row0 + rl < NN) { sloc[j] += v; s2loc[j] += v * v; }
      }
    }
  }

  if (stats) {
    #pragma unroll
    for (int j = 0; j < 4; ++j) {
      float a = sloc[j], b2 = s2loc[j];
      a  += __shfl_xor(a, 16, 64);  a  += __shfl_xor(a, 32, 64);
      b2 += __shfl_xor(b2, 16, 64); b2 += __shfl_xor(b2, 32, 64);
      if (q == 0) {
        int cl = wn * 64 + j * 16 + mm;
        atomicAdd(&sred[cl], a);
        atomicAdd(&sred[128 + cl], b2);
      }
    }
  }
  __syncthreads();

  #pragma unroll
  for (int pass = 0; pass < 8; ++pass) {
    int cidx = tid + pass * 256;          // 2048 chunks of 16B
    int r = cidx >> 4, kc = cidx & 15;
    int rr = row0 + r;
    if (rr < NN) {
      uint4 d = *(const uint4*)&cs[r * 136 + kc * 8];
      *(uint4*)&Ch[(size_t)rr * N + col0 + kc * 8] = d;
    }
  }

  if (stats && tid < 128) {
    atomicAdd(&stats[col0 + tid], sred[tid]);
    atomicAdd(&stats[N + col0 + tid], sred[128 + tid]);
  }
}

// ------------------------------------------------------------------
// Slim BN stats over fp16 tensor (stride == F)
// ------------------------------------------------------------------
__global__ __launch_bounds__(256) void k_stats16(const _Float16* __restrict__ X, int F,
                                                 float* __restrict__ sums) {
  int tid = threadIdx.x;
  int npf = F >> 8;
  float s[2] = {0.f, 0.f}, s2[2] = {0.f, 0.f};
  for (int r = blockIdx.x; r < NN; r += gridDim.x) {
    #pragma unroll
    for (int i = 0; i < 2; ++i) {
      if (i < npf) {
        float v = (float)X[(size_t)r * F + tid + i * 256];
        s[i] += v; s2[i] += v * v;
      }
    }
  }
  #pragma unroll
  for (int i = 0; i < 2; ++i) {
    if (i < npf) {
      atomicAdd(&sums[tid + i * 256], s[i]);
      atomicAdd(&sums[F + tid + i * 256], s2[i]);
    }
  }
}

// ------------------------------------------------------------------
// L5 BN fold for pooling
// ------------------------------------------------------------------
__global__ __launch_bounds__(1024) void k_prep(const float* __restrict__ sums,
                                               const float* __restrict__ g5,
                                               const float* __restrict__ be5,
                                               const float* __restrict__ Wg,
                                               const float* __restrict__ bg,
                                               float* __restrict__ sc, float* __restrict__ sh,
                                               float* __restrict__ scWg, float* __restrict__ gconst) {
  __shared__ float red[1024];
  int f = threadIdx.x;
  const float inv_n = 1.f / NN;
  float mean = sums[f] * inv_n;
  float var  = sums[1024 + f] * inv_n - mean * mean;
  float s = g5[f] * rsqrtf(var + EPS_BN);
  float h = be5[f] - mean * s;
  sc[f] = s; sh[f] = h;
  float wgf = Wg[f];
  scWg[f] = s * wgf;
  red[f] = h * wgf;
  __syncthreads();
  for (int o = 512; o > 0; o >>= 1) {
    if (f < o) red[f] += red[f + o];
    __syncthreads();
  }
  if (f == 0) gconst[0] = red[0] + bg[0];
}

__global__ __launch_bounds__(256) void k_gate_aff(const _Float16* __restrict__ X,
                                                  const float* __restrict__ scWg,
                                                  const float* __restrict__ gconst,
                                                  float* __restrict__ gate) {
  __shared__ float red[256];
  int n = blockIdx.x, tid = threadIdx.x;
  int f = tid * 4;
  uint2 u = *(const uint2*)(X + (size_t)n * 1024 + f);
  half2v h0 = __builtin_bit_cast(half2v, u.x);
  half2v h1 = __builtin_bit_cast(half2v, u.y);
  float s = (float)h0[0] * scWg[f] + (float)h0[1] * scWg[f + 1]
          + (float)h1[0] * scWg[f + 2] + (float)h1[1] * scWg[f + 3];
  red[tid] = s;
  __syncthreads();
  for (int o = 128; o > 0; o >>= 1) {
    if (tid < o) red[tid] += red[tid + o];
    __syncthreads();
  }
  if (tid == 0) gate[n] = red[0] + gconst[0];
}

__global__ __launch_bounds__(64) void k_segred(const float* __restrict__ gate,
                                               const int* __restrict__ goff,
                                               float* __restrict__ gmax,
                                               float* __restrict__ gsum) {
  int g = blockIdx.x, tid = threadIdx.x;
  int beg = goff[g], end = goff[g + 1];
  float m = -3.4e38f;
  for (int n = beg + tid; n < end; n += 64) m = fmaxf(m, gate[n]);
  for (int o = 32; o > 0; o >>= 1) m = fmaxf(m, __shfl_down(m, o, 64));
  m = __shfl(m, 0, 64);
  float s = 0.f;
  for (int n = beg + tid; n < end; n += 64) s += expf(gate[n] - m);
  for (int o = 32; o > 0; o >>= 1) s += __shfl_down(s, o, 64);
  if (tid == 0) { gmax[g] = m; gsum[g] = s; }
}

__global__ __launch_bounds__(256) void k_pool_aff(const _Float16* __restrict__ X,
                                                  const float* __restrict__ gate,
                                                  const int* __restrict__ goff,
                                                  const float* __restrict__ gmax,
                                                  const float* __restrict__ gsum,
                                                  const float* __restrict__ sc,
                                                  const float* __restrict__ sh,
                                                  float* __restrict__ pooled) {
  int g = blockIdx.x, tid = threadIdx.x;
  int beg = goff[g], end = goff[g + 1];
  int f = tid * 4;
  float acc[4] = {0.f, 0.f, 0.f, 0.f};
  bool nonempty = end > beg;
  if (nonempty) {
    float m = gmax[g], inv = 1.f / gsum[g];
    for (int n = beg; n < end; ++n) {
      float a = expf(gate[n] - m) * inv;
      uint2 u = *(const uint2*)(X + (size_t)n * 1024 + f);
      half2v h0 = __builtin_bit_cast(half2v, u.x);
      half2v h1 = __builtin_bit_cast(half2v, u.y);
      acc[0] += a * (float)h0[0];
      acc[1] += a * (float)h0[1];
      acc[2] += a * (float)h1[0];
      acc[3] += a * (float)h1[1];
    }
  }
  #pragma unroll
  for (int i = 0; i < 4; ++i) {
    int ff = f + i;
    float v = nonempty ? (acc[i] * sc[ff] + sh[ff]) : 0.f;
    pooled[(size_t)g * 1024 + ff] = v;
  }
}

// ------------------------------------------------------------------
// MLP head
// ------------------------------------------------------------------
__global__ __launch_bounds__(128) void k_head(const float* __restrict__ pooled,
                                              const float* __restrict__ Wf2, const float* __restrict__ bf2,
                                              const float* __restrict__ Wf3, const float* __restrict__ bf3,
                                              const float* __restrict__ Wf4, const float* __restrict__ bf4,
                                              float* __restrict__ out) {
  __shared__ float sp[1024];
  __shared__ float sp2[128];
  __shared__ float sp3[16];
  int g = blockIdx.x, tid = threadIdx.x;
  #pragma unroll
  for (int i = 0; i < 8; ++i) sp[tid + i * 128] = pooled[(size_t)g * 1024 + tid + i * 128];
  __syncthreads();
  float s = bf2[tid];
  for (int k = 0; k < 1024; ++k) s += sp[k] * Wf2[k * 128 + tid];
  sp2[tid] = fmaxf(s, 0.f);
  __syncthreads();
  if (tid < 16) {
    float t = bf3[tid];
    for (int k = 0; k < 128; ++k) t += sp2[k] * Wf3[k * 16 + tid];
    sp3[tid] = fmaxf(t, 0.f);
  }
  __syncthreads();
  if (tid == 0) {
    float t = bf4[0];
    for (int k = 0; k < 16; ++k) t += sp3[k] * Wf4[k];
    out[g] = t;
  }
}

// ------------------------------------------------------------------
extern "C" void kernel_launch(void* const* d_in, const int* in_sizes, int n_in,
                              void* d_out, int out_size, void* d_ws, size_t ws_size,
                              hipStream_t stream) {
  const float* x     = (const float*)d_in[0];
  const int*   ei    = (const int*)d_in[1];
  const int*   batch = (const int*)d_in[2];
  const float* W[5]; const float* b[5]; const float* g[5]; const float* be[5];
  for (int l = 0; l < 5; ++l) {
    W[l]  = (const float*)d_in[3 + 4 * l];
    b[l]  = (const float*)d_in[4 + 4 * l];
    g[l]  = (const float*)d_in[5 + 4 * l];
    be[l] = (const float*)d_in[6 + 4 * l];
  }
  const float* Wg  = (const float*)d_in[23];
  const float* bg  = (const float*)d_in[24];
  const float* Wf2 = (const float*)d_in[25];
  const float* bf2 = (const float*)d_in[26];
  const float* Wf3 = (const float*)d_in[27];
  const float* bf3 = (const float*)d_in[28];
  const float* Wf4 = (const float*)d_in[29];
  const float* bf4 = (const float*)d_in[30];
  float* out = (float*)d_out;

  const int* row = ei;
  const int* col = ei + NE;

  char* base = (char*)d_ws;
  size_t off = 0;
  auto alloc = [&](size_t bytes) -> char* {
    char* p = base + off;
    off = (off + bytes + 255) & ~(size_t)255;
    return p;
  };
  _Float16*  AH  = (_Float16*)alloc((size_t)MPAD * 1024 * 2); // GEMM A operand / r2 / a4 / a5
  _Float16*  ASM = (_Float16*)alloc((size_t)MPAD * 32 * 2);   // L1 A operand
  _Float16*  BF  = (_Float16*)alloc((size_t)NN * 512 * 2);    // gather buffer
  _Float16*  BF2 = (_Float16*)alloc((size_t)NN * 512 * 2);    // gather buffer
  _Float16*  H5  = (_Float16*)alloc((size_t)NN * 1024 * 2);   // r5 fp16
  const int wtsz[5] = {1024 * 32, 512 * 1024, 256 * 512, 512 * 256, 1024 * 512};
  _Float16* WT[5];
  for (int l = 0; l < 5; ++l) WT[l] = (_Float16*)alloc((size_t)wtsz[l] * 2);
  float* c2  = (float*)alloc(512 * 4);
  float* c3  = (float*)alloc(256 * 4);
  float* dinv    = (float*)alloc(NN * 4);
  int*   indptr  = (int*)alloc((NN + 1) * 4);
  int*   cursor  = (int*)alloc(NN * 4);
  int2*  csw     = (int2*)alloc((size_t)NTOT * 8);
  int*   psum    = (int*)alloc((NBLK + 1) * 4);
  int*   pbase   = (int*)alloc((NBLK + 1) * 4);
  int*   goff    = (int*)alloc((NG + 1) * 4);
  float* gate    = (float*)alloc(NN * 4);
  float* gmax    = (float*)alloc(NG * 4);
  float* gsum    = (float*)alloc(NG * 4);
  float* pooled  = (float*)alloc((size_t)NG * 1024 * 4);
  float* scv5 = (float*)alloc(1024 * 4);
  float* shv5 = (float*)alloc(1024 * 4);
  float* scWg = (float*)alloc(1024 * 4);
  float* gconst = (float*)alloc(4);
  // single zeroed region: bns(6656) | deg(NN) | gcnt(NG) | rsum(NN)
  size_t znf = 6656 + NN + NG + NN;
  float* zbase = (float*)alloc(znf * 4);
  float* bns  = zbase;
  int*   deg  = (int*)(zbase + 6656);
  int*   gcnt = (int*)(zbase + 6656 + NN);
  float* rsum = zbase + 6656 + NN + NG;
  float* bns1 = bns;          // F=1024
  float* bns2 = bns + 2048;   // F=512
  float* bns3 = bns + 3072;   // F=256
  float* bns4 = bns + 3584;   // F=512
  float* bns5 = bns + 4608;   // F=1024

  // ---- preprocessing ----
  hipMemsetAsync(zbase, 0, znf * 4, stream);
  k_deg<<<(NTOT + 255) / 256, 256, 0, stream>>>(col, deg, batch, gcnt);
  k_pre1<<<NBLK, 256, 0, stream>>>(deg, dinv, psum);
  k_pre2<<<1, 256, 0, stream>>>(psum, pbase, gcnt, goff);
  k_pre3<<<NBLK, 256, 0, stream>>>(deg, pbase, indptr, cursor);
  k_fill<<<(NTOT + 255) / 256, 256, 0, stream>>>(row, col, dinv, cursor, csw, rsum);
  k_wconv3<<<2688, 256, 0, stream>>>(W[0], W[3], W[4], WT[0], WT[3], WT[4]);

  auto gemm = [&](const _Float16* Aop, int wl, const float* bias,
                  _Float16* Ch, float* stats, int Nn, int Kk, int relu) {
    int nbx = Nn / 128;
    dim3 grid(nbx * 160);
    if      (Kk == 32)   k_gemmg<32>  <<<grid, 256, 0, stream>>>(Aop, WT[wl], bias, Ch, stats, Nn, relu, nbx);
    else if (Kk == 256)  k_gemmg<256> <<<grid, 256, 0, stream>>>(Aop, WT[wl], bias, Ch, stats, Nn, relu, nbx);
    else if (Kk == 512)  k_gemmg<512> <<<grid, 256, 0, stream>>>(Aop, WT[wl], bias, Ch, stats, Nn, relu, nbx);
    else                 k_gemmg<1024><<<grid, 256, 0, stream>>>(Aop, WT[wl], bias, Ch, stats, Nn, relu, nbx);
  };

  // ---- layer 1 (29 -> 1024): agg-first; GEMM1 fuses bias/relu/stats ----
  k_agg29<<<NN, AGG_T, 0, stream>>>(x, indptr, csw, ASM);
  gemm(ASM, 0, b[0], AH, bns1, 1024, 32, 1);                     // r1 fp16

  // ---- layer 2 (1024 -> 512): BN1 folded into W2; transform-first ----
  k_wfold<<<512, 256, 0, stream>>>(W[1], 1024, 512, bns1, g[0], be[0], WT[1], c2);
  gemm(AH, 1, nullptr, BF, nullptr, 512, 1024, 0);               // G2
  k_aggv<8, 0><<<NN / 4, 256, 0, stream>>>(BF, AH, indptr, csw, rsum, c2, b[1], nullptr); // r2
  k_stats16<<<512, 256, 0, stream>>>(AH, 512, bns2);

  // ---- layer 3 (512 -> 256): BN2 folded into W3; transform-first ----
  k_wfold<<<256, 256, 0, stream>>>(W[2], 512, 256, bns2, g[1], be[1], WT[2], c3);
  gemm(AH, 2, nullptr, BF2, nullptr, 256, 512, 0);               // G3
  k_aggv<4, 0><<<NN / 4, 256, 0, stream>>>(BF2, BF, indptr, csw, rsum, c3, b[2], nullptr); // r3
  k_stats16<<<512, 256, 0, stream>>>(BF, 256, bns3);

  // ---- layer 4 (256 -> 512): agg-first, BN3 inline in agg epilogue ----
  k_aggv<4, 1><<<NN / 4, 256, 0, stream>>>(BF, AH, indptr, csw, rsum, bns3, g[2], be[2]); // a4
  gemm(AH, 3, b[3], BF2, bns4, 512, 256, 1);                     // r4 fp16 + stats

  // ---- layer 5 (512 -> 1024): agg-first, BN4 inline; GEMM5 fp16 out ----
  k_aggv<8, 1><<<NN / 4, 256, 0, stream>>>(BF2, AH, indptr, csw, rsum, bns4, g[3], be[3]); // a5
  gemm(AH, 4, b[4], H5, bns5, 1024, 512, 1);                     // r5 fp16 + stats

  // ---- attention pooling with folded BN5 affine ----
  k_prep<<<1, 1024, 0, stream>>>(bns5, g[4], be[4], Wg, bg, scv5, shv5, scWg, gconst);
  k_gate_aff<<<NN, 256, 0, stream>>>(H5, scWg, gconst, gate);
  k_segred<<<NG, 64, 0, stream>>>(gate, goff, gmax, gsum);
  k_pool_aff<<<NG, 256, 0, stream>>>(H5, gate, goff, gmax, gsum, scv5, shv5, pooled);

  // ---- MLP head ----
  k_head<<<NG, 128, 0, stream>>>(pooled, Wf2, bf2, Wf3, bf3, Wf4, bf4, out);
}

// Round 9
// 646.468 us; speedup vs baseline: 1.1661x; 1.1661x over previous
//
#include <hip/hip_runtime.h>

#define EPS_BN 1e-5f

constexpr int NN   = 20000;       // nodes
constexpr int NE   = 320000;      // edges
constexpr int NTOT = NE + NN;     // edges + self loops
constexpr int NG   = 512;         // graphs
constexpr int MPAD = 20480;       // 160 * 128 rows
constexpr int NBLK = 79;          // ceil(NN/256)

typedef _Float16 half8  __attribute__((ext_vector_type(8)));
typedef _Float16 half2v __attribute__((ext_vector_type(2)));
typedef float floatx4   __attribute__((ext_vector_type(4)));

__device__ __forceinline__ void gload_lds16(const void* g, void* l) {
  __builtin_amdgcn_global_load_lds(
      (const __attribute__((address_space(1))) void*)g,
      (__attribute__((address_space(3))) void*)l, 16, 0, 0);
}

// ------------------------------------------------------------------
// Graph preprocessing
// ------------------------------------------------------------------
__global__ void k_deg(const int* __restrict__ col, int* __restrict__ deg,
                      const int* __restrict__ batch, int* __restrict__ gcnt) {
  int e = blockIdx.x * blockDim.x + threadIdx.x;
  if (e >= NTOT) return;
  int c = (e < NE) ? col[e] : (e - NE);
  atomicAdd(&deg[c], 1);
  if (e < NN) atomicAdd(&gcnt[batch[e]], 1);
}

// phase 1: per-block sums of deg + dinv
__global__ __launch_bounds__(256) void k_pre1(const int* __restrict__ deg,
                                              float* __restrict__ dinvv,
                                              int* __restrict__ psum) {
  __shared__ int ws[4];
  int t = threadIdx.x, lane = t & 63, wv = t >> 6;
  int idx = blockIdx.x * 256 + t;
  int d = (idx < NN) ? deg[idx] : 0;
  if (idx < NN) dinvv[idx] = rsqrtf((float)d);
  int s = d;
  for (int o = 1; o < 64; o <<= 1) { int u = __shfl_up(s, o, 64); if (lane >= o) s += u; }
  if (lane == 63) ws[wv] = s;
  __syncthreads();
  if (t == 0) psum[blockIdx.x] = ws[0] + ws[1] + ws[2] + ws[3];
}

// phase 2: scan the NBLK partials + scan gcnt (512) in one small block
__global__ __launch_bounds__(256) void k_pre2(const int* __restrict__ psum,
                                              int* __restrict__ pbase,
                                              const int* __restrict__ gcnt,
                                              int* __restrict__ goff) {
  __shared__ int ws[8];
  int t = threadIdx.x, lane = t & 63, wv = t >> 6;
  int v = (t < NBLK) ? psum[t] : 0;
  int inc = v;
  for (int o = 1; o < 64; o <<= 1) { int u = __shfl_up(inc, o, 64); if (lane >= o) inc += u; }
  if (lane == 63) ws[wv] = inc;
  __syncthreads();
  int base = 0;
  for (int w = 0; w < wv; ++w) base += ws[w];
  int excl = base + inc - v;
  if (t < NBLK) pbase[t] = excl;
  if (t == NBLK - 1) pbase[NBLK] = excl + v;
  __syncthreads();
  int a0 = gcnt[2 * t], a1 = gcnt[2 * t + 1];
  int p = a0 + a1;
  int incp = p;
  for (int o = 1; o < 64; o <<= 1) { int u = __shfl_up(incp, o, 64); if (lane >= o) incp += u; }
  if (lane == 63) ws[4 + wv] = incp;
  __syncthreads();
  int gb = 0;
  for (int w = 0; w < wv; ++w) gb += ws[4 + w];
  int exclp = gb + incp - p;
  goff[2 * t]     = exclp;
  goff[2 * t + 1] = exclp + a0;
  if (t == 255) goff[NG] = exclp + p;
}

// phase 3: emit indptr/cursor
__global__ __launch_bounds__(256) void k_pre3(const int* __restrict__ deg,
                                              const int* __restrict__ pbase,
                                              int* __restrict__ indptr,
                                              int* __restrict__ cursor) {
  __shared__ int ws[4];
  int t = threadIdx.x, lane = t & 63, wv = t >> 6;
  int idx = blockIdx.x * 256 + t;
  int d = (idx < NN) ? deg[idx] : 0;
  int inc = d;
  for (int o = 1; o < 64; o <<= 1) { int u = __shfl_up(inc, o, 64); if (lane >= o) inc += u; }
  if (lane == 63) ws[wv] = inc;
  __syncthreads();
  int base = pbase[blockIdx.x];
  for (int w = 0; w < wv; ++w) base += ws[w];
  int excl = base + inc - d;
  if (idx < NN) { indptr[idx] = excl; cursor[idx] = excl; }
  if (idx == NN - 1) indptr[NN] = excl + d;
}

// CSR fill with packed {src, w_bits} meta + rowsum
__global__ void k_fill(const int* __restrict__ row, const int* __restrict__ col,
                       const float* __restrict__ dinv, int* __restrict__ cursor,
                       int2* __restrict__ csw, float* __restrict__ rsum) {
  int e = blockIdx.x * blockDim.x + threadIdx.x;
  if (e >= NTOT) return;
  int r, c;
  if (e < NE) { r = row[e]; c = col[e]; } else { r = c = e - NE; }
  float wv = dinv[r] * dinv[c];
  int pos = atomicAdd(&cursor[c], 1);
  int2 m; m.x = r; m.y = __builtin_bit_cast(int, wv);
  csw[pos] = m;
  atomicAdd(&rsum[c], wv);
}

// ------------------------------------------------------------------
// Weight transposes (W1 pad 29->32, W4, W5) in one kernel
// ------------------------------------------------------------------
__global__ void k_wconv3(const float* __restrict__ W0, const float* __restrict__ W3,
                         const float* __restrict__ W4,
                         _Float16* __restrict__ T0, _Float16* __restrict__ T3,
                         _Float16* __restrict__ T4) {
  int idx = blockIdx.x * blockDim.x + threadIdx.x;
  if (idx < 32768) {                       // W1: K=29 (pad 32), N=1024
    int n = idx >> 5, k = idx & 31;
    T0[idx] = (_Float16)((k < 29) ? W0[(size_t)k * 1024 + n] : 0.f);
  } else if (idx < 32768 + 131072) {       // W4: K=256, N=512
    int j = idx - 32768;
    int n = j >> 8, k = j & 255;
    T3[j] = (_Float16)W3[(size_t)k * 512 + n];
  } else if (idx < 32768 + 131072 + 524288) { // W5: K=512, N=1024
    int j = idx - 163840;
    int n = j >> 9, k = j & 511;
    T4[j] = (_Float16)W4[(size_t)k * 1024 + n];
  }
}

// W' = diag(sc) W transposed to [N,K] fp16; c[n] = sum_k sh_k W[k,n]
__global__ __launch_bounds__(256) void k_wfold(const float* __restrict__ W, int K, int N,
                                               const float* __restrict__ sums,
                                               const float* __restrict__ gamma,
                                               const float* __restrict__ beta,
                                               _Float16* __restrict__ T,
                                               float* __restrict__ c) {
  __shared__ float red[256];
  int n = blockIdx.x, tid = threadIdx.x;
  const float inv_n = 1.f / NN;
  float csum = 0.f;
  for (int k = tid; k < K; k += 256) {
    float mean = sums[k] * inv_n;
    float var  = sums[K + k] * inv_n - mean * mean;
    float sc   = gamma[k] * rsqrtf(var + EPS_BN);
    float sh   = beta[k] - mean * sc;
    float wv   = W[(size_t)k * N + n];
    T[(size_t)n * K + k] = (_Float16)(sc * wv);
    csum += sh * wv;
  }
  red[tid] = csum;
  __syncthreads();
  for (int o = 128; o > 0; o >>= 1) {
    if (tid < o) red[tid] += red[tid + o];
    __syncthreads();
  }
  if (tid == 0) c[n] = red[0];
}

// ------------------------------------------------------------------
// L1 aggregation: fp32 x (F=29) -> fp16 out (stride 32)
// ------------------------------------------------------------------
#define AGG_T  128
#define AGG_CH 128
__global__ __launch_bounds__(AGG_T) void k_agg29(
    const float* __restrict__ X,
    const int* __restrict__ indptr, const int2* __restrict__ csw,
    _Float16* __restrict__ Y) {
  __shared__ int   s_src[AGG_CH];
  __shared__ float s_w[AGG_CH];
  int node = blockIdx.x;
  int tid  = threadIdx.x;
  int beg = indptr[node], end = indptr[node + 1];
  float acc = 0.f;
  for (int e0 = beg; e0 < end; e0 += AGG_CH) {
    int c = min(AGG_CH, end - e0);
    if (tid < c) {
      int2 m = csw[e0 + tid];
      s_src[tid] = m.x;
      s_w[tid]   = __builtin_bit_cast(float, m.y);
    }
    __syncthreads();
    for (int j = 0; j < c; ++j) {
      if (tid < 29) acc += s_w[j] * X[(size_t)s_src[j] * 29 + tid];
    }
    __syncthreads();
  }
  if (tid < 32) Y[(size_t)node * 32 + tid] = (tid < 29) ? (_Float16)acc : (_Float16)0.f;
}

// ------------------------------------------------------------------
// Whole-row fp16 gather aggregation, wave-per-node (4 nodes/block).
// Unroll-8 for memory parallelism.
// MODE 0: out = relu(acc + s*p0[f] + p1[f])
// MODE 1: out = sc[f]*acc + s*sh[f]  (BN from sums p0, gamma p1, beta p2)
// ------------------------------------------------------------------
template<int VEC, int MODE>
__global__ __launch_bounds__(256) void k_aggv(
    const _Float16* __restrict__ X, _Float16* __restrict__ Y,
    const int* __restrict__ indptr, const int2* __restrict__ csw,
    const float* __restrict__ rowsum,
    const float* __restrict__ p0, const float* __restrict__ p1,
    const float* __restrict__ p2)
{
  constexpr int F = 64 * VEC;
  int wave = threadIdx.x >> 6;
  int lane = threadIdx.x & 63;
  int node = blockIdx.x * 4 + wave;
  int beg = indptr[node], end = indptr[node + 1];
  float acc[VEC];
  #pragma unroll
  for (int i = 0; i < VEC; ++i) acc[i] = 0.f;
  const unsigned* Xl = (const unsigned*)X + lane * (VEC / 2);

  auto body = [&](int e) {
    int2 m = csw[e];
    float we = __builtin_bit_cast(float, m.y);
    const unsigned* xr = Xl + (size_t)m.x * (F / 2);
    unsigned uu[VEC / 2];
    if constexpr (VEC == 8) {
      uint4 d = *(const uint4*)xr;
      uu[0] = d.x; uu[1] = d.y; uu[2] = d.z; uu[3] = d.w;
    } else {
      uint2 d = *(const uint2*)xr;
      uu[0] = d.x; uu[1] = d.y;
    }
    #pragma unroll
    for (int i = 0; i < VEC / 2; ++i) {
      half2v h = __builtin_bit_cast(half2v, uu[i]);
      acc[2 * i]     = fmaf(we, (float)h[0], acc[2 * i]);
      acc[2 * i + 1] = fmaf(we, (float)h[1], acc[2 * i + 1]);
    }
  };
  int e = beg;
  for (; e + 8 <= end; e += 8) {
    body(e); body(e + 1); body(e + 2); body(e + 3);
    body(e + 4); body(e + 5); body(e + 6); body(e + 7);
  }
  for (; e < end; ++e) body(e);

  float s_n = rowsum[node];
  size_t ob = (size_t)node * F + lane * VEC;
  _Float16 outv[VEC];
  #pragma unroll
  for (int i = 0; i < VEC; ++i) {
    int f = lane * VEC + i;
    float v;
    if constexpr (MODE == 0) {
      v = fmaxf(acc[i] + s_n * p0[f] + p1[f], 0.f);
    } else {
      const float inv_n = 1.f / NN;
      float mean = p0[f] * inv_n;
      float var  = p0[F + f] * inv_n - mean * mean;
      float sc   = p1[f] * rsqrtf(var + EPS_BN);
      float sh   = p2[f] - mean * sc;
      v = sc * acc[i] + s_n * sh;
    }
    outv[i] = (_Float16)v;
  }
  if constexpr (VEC == 8) *(uint4*)(Y + ob) = *(const uint4*)outv;
  else                    *(uint2*)(Y + ob) = *(const uint2*)outv;
}

// ------------------------------------------------------------------
// fp16 MFMA GEMM, 128x128 tile, XCD-swizzled grid, XOR-swizzled LDS,
// LDS-coalesced fp16 epilogue (proven round-7 configuration).
// A: [MPAD,K] fp16. B^T: [N,K] fp16. Out fp16 Ch; fused bias/relu +
// optional BN stats (rows < NN only).
// ------------------------------------------------------------------
template<int BK>
__global__ __launch_bounds__(256) void k_gemm16(
    const _Float16* __restrict__ A, const _Float16* __restrict__ B,
    const float* __restrict__ bias,
    _Float16* __restrict__ Ch,
    float* __restrict__ stats,
    int N, int K, int do_relu, int nbx)
{
  __shared__ __align__(16) union UU {
    struct { _Float16 a[128 * BK]; _Float16 b[128 * BK]; } ab;
    _Float16 c[128 * 136];          // 136-elem padded rows (16B-aligned)
  } u;
  __shared__ float sred[256];

  const int tid  = threadIdx.x;
  const int wave = tid >> 6;
  const int lane = tid & 63;

  int lin = blockIdx.x;
  int xcd = lin & 7, seq = lin >> 3;
  int bx = seq % nbx, grp = seq / nbx;
  int by = xcd + 8 * grp;            // 0..159
  const int row0 = by * 128;
  const int col0 = bx * 128;

  const int q  = lane >> 4;
  const int mm = lane & 15;
  const int wm = wave >> 1;
  const int wn = wave & 1;

  sred[tid] = 0.f;

  constexpr int NREP = (BK == 32) ? 2 : 4;
  constexpr int RPW  = (BK == 32) ? 16 : 8;
  const _Float16* pA[NREP];
  const _Float16* pB[NREP];
  _Float16* dstA[NREP];
  _Float16* dstB[NREP];
  {
    int rl = (BK == 32) ? (lane >> 2) : (lane >> 3);
    int cp = (BK == 32) ? (lane & 3) : (lane & 7);
    #pragma unroll
    for (int rep = 0; rep < NREP; ++rep) {
      int trow = wave * 32 + rep * RPW;
      int s = (BK == 32) ? ((lane >> 3) & 3) : ((rep & 1) * 4 + (rl >> 1));
      int csrc = cp ^ s;
      pA[rep] = A + (size_t)(row0 + trow + rl) * K + csrc * 8;
      pB[rep] = B + (size_t)(col0 + trow + rl) * K + csrc * 8;
      dstA[rep] = u.ab.a + trow * BK;
      dstB[rep] = u.ab.b + trow * BK;
    }
  }

  const int sR = (BK == 32) ? ((mm >> 1) & 3) : (mm >> 1);
  int rdA[4], rdB[4];
  #pragma unroll
  for (int i = 0; i < 4; ++i) {
    rdA[i] = (wm * 64 + i * 16 + mm) * BK;
    rdB[i] = (wn * 64 + i * 16 + mm) * BK;
  }

  floatx4 acc[4][4];
  #pragma unroll
  for (int i = 0; i < 4; ++i)
    #pragma unroll
    for (int j = 0; j < 4; ++j) acc[i][j] = floatx4{0.f, 0.f, 0.f, 0.f};

  for (int k0 = 0; k0 < K; k0 += BK) {
    #pragma unroll
    for (int rep = 0; rep < NREP; ++rep) {
      gload_lds16(pA[rep], dstA[rep]);
      gload_lds16(pB[rep], dstB[rep]);
      pA[rep] += BK; pB[rep] += BK;
    }
    __syncthreads();

    #pragma unroll
    for (int kk = 0; kk < BK / 32; ++kk) {
      int pos = ((q + 4 * kk) ^ sR) * 8;
      half8 av[4];
      #pragma unroll
      for (int i = 0; i < 4; ++i) av[i] = *(const half8*)&u.ab.a[rdA[i] + pos];
      #pragma unroll
      for (int j = 0; j < 4; ++j) {
        half8 bv = *(const half8*)&u.ab.b[rdB[j] + pos];
        #pragma unroll
        for (int i = 0; i < 4; ++i)
          acc[i][j] = __builtin_amdgcn_mfma_f32_16x16x32_f16(av[i], bv, acc[i][j], 0, 0, 0);
      }
    }
    __syncthreads();
  }

  // epilogue: fragments -> LDS tile (+stats), then coalesced stores
  float sloc[4]  = {0.f, 0.f, 0.f, 0.f};
  float s2loc[4] = {0.f, 0.f, 0.f, 0.f};
  #pragma unroll
  for (int j = 0; j < 4; ++j) {
    int cl = wn * 64 + j * 16 + mm;
    float bv = bias ? bias[col0 + cl] : 0.f;
    #pragma unroll
    for (int i = 0; i < 4; ++i) {
      #pragma unroll
      for (int r = 0; r < 4; ++r) {
        int rl = wm * 64 + i * 16 + q * 4 + r;
        float v = acc[i][j][r] + bv;
        if (do_relu) v = fmaxf(v, 0.f);
        u.c[rl * 136 + cl] = (_Float16)v;
        if (row0 + rl < NN) { sloc[j] += v; s2loc[j] += v * v; }
      }
    }
  }

  if (stats) {
    #pragma unroll
    for (int j = 0; j < 4; ++j) {
      float a = sloc[j], b2 = s2loc[j];
      a  += __shfl_xor(a, 16, 64);  a  += __shfl_xor(a, 32, 64);
      b2 += __shfl_xor(b2, 16, 64); b2 += __shfl_xor(b2, 32, 64);
      if (q == 0) {
        int cl = wn * 64 + j * 16 + mm;
        atomicAdd(&sred[cl], a);
        atomicAdd(&sred[128 + cl], b2);
      }
    }
  }
  __syncthreads();

  #pragma unroll
  for (int pass = 0; pass < 8; ++pass) {
    int cidx = tid + pass * 256;          // 2048 chunks of 16B
    int r = cidx >> 4, kc = cidx & 15;
    int rr = row0 + r;
    if (rr < NN) {
      uint4 d = *(const uint4*)&u.c[r * 136 + kc * 8];
      *(uint4*)&Ch[(size_t)rr * N + col0 + kc * 8] = d;
    }
  }

  if (stats && tid < 128) {
    atomicAdd(&stats[col0 + tid], sred[tid]);
    atomicAdd(&stats[N + col0 + tid], sred[128 + tid]);
  }
}

// ------------------------------------------------------------------
// Slim BN stats over fp16 tensor (stride == F)
// ------------------------------------------------------------------
__global__ __launch_bounds__(256) void k_stats16(const _Float16* __restrict__ X, int F,
                                                 float* __restrict__ sums) {
  int tid = threadIdx.x;
  int npf = F >> 8;
  float s[2] = {0.f, 0.f}, s2[2] = {0.f, 0.f};
  for (int r = blockIdx.x; r < NN; r += gridDim.x) {
    #pragma unroll
    for (int i = 0; i < 2; ++i) {
      if (i < npf) {
        float v = (float)X[(size_t)r * F + tid + i * 256];
        s[i] += v; s2[i] += v * v;
      }
    }
  }
  #pragma unroll
  for (int i = 0; i < 2; ++i) {
    if (i < npf) {
      atomicAdd(&sums[tid + i * 256], s[i]);
      atomicAdd(&sums[F + tid + i * 256], s2[i]);
    }
  }
}

// ------------------------------------------------------------------
// L5 BN fold for pooling
// ------------------------------------------------------------------
__global__ __launch_bounds__(1024) void k_prep(const float* __restrict__ sums,
                                               const float* __restrict__ g5,
                                               const float* __restrict__ be5,
                                               const float* __restrict__ Wg,
                                               const float* __restrict__ bg,
                                               float* __restrict__ sc, float* __restrict__ sh,
                                               float* __restrict__ scWg, float* __restrict__ gconst) {
  __shared__ float red[1024];
  int f = threadIdx.x;
  const float inv_n = 1.f / NN;
  float mean = sums[f] * inv_n;
  float var  = sums[1024 + f] * inv_n - mean * mean;
  float s = g5[f] * rsqrtf(var + EPS_BN);
  float h = be5[f] - mean * s;
  sc[f] = s; sh[f] = h;
  float wgf = Wg[f];
  scWg[f] = s * wgf;
  red[f] = h * wgf;
  __syncthreads();
  for (int o = 512; o > 0; o >>= 1) {
    if (f < o) red[f] += red[f + o];
    __syncthreads();
  }
  if (f == 0) gconst[0] = red[0] + bg[0];
}

__global__ __launch_bounds__(256) void k_gate_aff(const _Float16* __restrict__ X,
                                                  const float* __restrict__ scWg,
                                                  const float* __restrict__ gconst,
                                                  float* __restrict__ gate) {
  __shared__ float red[256];
  int n = blockIdx.x, tid = threadIdx.x;
  int f = tid * 4;
  uint2 u = *(const uint2*)(X + (size_t)n * 1024 + f);
  half2v h0 = __builtin_bit_cast(half2v, u.x);
  half2v h1 = __builtin_bit_cast(half2v, u.y);
  float s = (float)h0[0] * scWg[f] + (float)h0[1] * scWg[f + 1]
          + (float)h1[0] * scWg[f + 2] + (float)h1[1] * scWg[f + 3];
  red[tid] = s;
  __syncthreads();
  for (int o = 128; o > 0; o >>= 1) {
    if (tid < o) red[tid] += red[tid + o];
    __syncthreads();
  }
  if (tid == 0) gate[n] = red[0] + gconst[0];
}

__global__ __launch_bounds__(64) void k_segred(const float* __restrict__ gate,
                                               const int* __restrict__ goff,
                                               float* __restrict__ gmax,
                                               float* __restrict__ gsum) {
  int g = blockIdx.x, tid = threadIdx.x;
  int beg = goff[g], end = goff[g + 1];
  float m = -3.4e38f;
  for (int n = beg + tid; n < end; n += 64) m = fmaxf(m, gate[n]);
  for (int o = 32; o > 0; o >>= 1) m = fmaxf(m, __shfl_down(m, o, 64));
  m = __shfl(m, 0, 64);
  float s = 0.f;
  for (int n = beg + tid; n < end; n += 64) s += expf(gate[n] - m);
  for (int o = 32; o > 0; o >>= 1) s += __shfl_down(s, o, 64);
  if (tid == 0) { gmax[g] = m; gsum[g] = s; }
}

__global__ __launch_bounds__(256) void k_pool_aff(const _Float16* __restrict__ X,
                                                  const float* __restrict__ gate,
                                                  const int* __restrict__ goff,
                                                  const float* __restrict__ gmax,
                                                  const float* __restrict__ gsum,
                                                  const float* __restrict__ sc,
                                                  const float* __restrict__ sh,
                                                  float* __restrict__ pooled) {
  int g = blockIdx.x, tid = threadIdx.x;
  int beg = goff[g], end = goff[g + 1];
  int f = tid * 4;
  float acc[4] = {0.f, 0.f, 0.f, 0.f};
  bool nonempty = end > beg;
  if (nonempty) {
    float m = gmax[g], inv = 1.f / gsum[g];
    for (int n = beg; n < end; ++n) {
      float a = expf(gate[n] - m) * inv;
      uint2 u = *(const uint2*)(X + (size_t)n * 1024 + f);
      half2v h0 = __builtin_bit_cast(half2v, u.x);
      half2v h1 = __builtin_bit_cast(half2v, u.y);
      acc[0] += a * (float)h0[0];
      acc[1] += a * (float)h0[1];
      acc[2] += a * (float)h1[0];
      acc[3] += a * (float)h1[1];
    }
  }
  #pragma unroll
  for (int i = 0; i < 4; ++i) {
    int ff = f + i;
    float v = nonempty ? (acc[i] * sc[ff] + sh[ff]) : 0.f;
    pooled[(size_t)g * 1024 + ff] = v;
  }
}

// ------------------------------------------------------------------
// MLP head
// ------------------------------------------------------------------
__global__ __launch_bounds__(128) void k_head(const float* __restrict__ pooled,
                                              const float* __restrict__ Wf2, const float* __restrict__ bf2,
                                              const float* __restrict__ Wf3, const float* __restrict__ bf3,
                                              const float* __restrict__ Wf4, const float* __restrict__ bf4,
                                              float* __restrict__ out) {
  __shared__ float sp[1024];
  __shared__ float sp2[128];
  __shared__ float sp3[16];
  int g = blockIdx.x, tid = threadIdx.x;
  #pragma unroll
  for (int i = 0; i < 8; ++i) sp[tid + i * 128] = pooled[(size_t)g * 1024 + tid + i * 128];
  __syncthreads();
  float s = bf2[tid];
  for (int k = 0; k < 1024; ++k) s += sp[k] * Wf2[k * 128 + tid];
  sp2[tid] = fmaxf(s, 0.f);
  __syncthreads();
  if (tid < 16) {
    float t = bf3[tid];
    for (int k = 0; k < 128; ++k) t += sp2[k] * Wf3[k * 16 + tid];
    sp3[tid] = fmaxf(t, 0.f);
  }
  __syncthreads();
  if (tid == 0) {
    float t = bf4[0];
    for (int k = 0; k < 16; ++k) t += sp3[k] * Wf4[k];
    out[g] = t;
  }
}

// ------------------------------------------------------------------
extern "C" void kernel_launch(void* const* d_in, const int* in_sizes, int n_in,
                              void* d_out, int out_size, void* d_ws, size_t ws_size,
                              hipStream_t stream) {
  const float* x     = (const float*)d_in[0];
  const int*   ei    = (const int*)d_in[1];
  const int*   batch = (const int*)d_in[2];
  const float* W[5]; const float* b[5]; const float* g[5]; const float* be[5];
  for (int l = 0; l < 5; ++l) {
    W[l]  = (const float*)d_in[3 + 4 * l];
    b[l]  = (const float*)d_in[4 + 4 * l];
    g[l]  = (const float*)d_in[5 + 4 * l];
    be[l] = (const float*)d_in[6 + 4 * l];
  }
  const float* Wg  = (const float*)d_in[23];
  const float* bg  = (const float*)d_in[24];
  const float* Wf2 = (const float*)d_in[25];
  const float* bf2 = (const float*)d_in[26];
  const float* Wf3 = (const float*)d_in[27];
  const float* bf3 = (const float*)d_in[28];
  const float* Wf4 = (const float*)d_in[29];
  const float* bf4 = (const float*)d_in[30];
  float* out = (float*)d_out;

  const int* row = ei;
  const int* col = ei + NE;

  char* base = (char*)d_ws;
  size_t off = 0;
  auto alloc = [&](size_t bytes) -> char* {
    char* p = base + off;
    off = (off + bytes + 255) & ~(size_t)255;
    return p;
  };
  _Float16*  AH  = (_Float16*)alloc((size_t)MPAD * 1024 * 2); // GEMM A operand / r2 / a4 / a5
  _Float16*  ASM = (_Float16*)alloc((size_t)MPAD * 32 * 2);   // L1 A operand
  _Float16*  BF  = (_Float16*)alloc((size_t)NN * 512 * 2);    // gather buffer
  _Float16*  BF2 = (_Float16*)alloc((size_t)NN * 512 * 2);    // gather buffer
  _Float16*  H5  = (_Float16*)alloc((size_t)NN * 1024 * 2);   // r5 fp16
  const int wtsz[5] = {1024 * 32, 512 * 1024, 256 * 512, 512 * 256, 1024 * 512};
  _Float16* WT[5];
  for (int l = 0; l < 5; ++l) WT[l] = (_Float16*)alloc((size_t)wtsz[l] * 2);
  float* c2  = (float*)alloc(512 * 4);
  float* c3  = (float*)alloc(256 * 4);
  float* dinv    = (float*)alloc(NN * 4);
  int*   indptr  = (int*)alloc((NN + 1) * 4);
  int*   cursor  = (int*)alloc(NN * 4);
  int2*  csw     = (int2*)alloc((size_t)NTOT * 8);
  int*   psum    = (int*)alloc((NBLK + 1) * 4);
  int*   pbase   = (int*)alloc((NBLK + 1) * 4);
  int*   goff    = (int*)alloc((NG + 1) * 4);
  float* gate    = (float*)alloc(NN * 4);
  float* gmax    = (float*)alloc(NG * 4);
  float* gsum    = (float*)alloc(NG * 4);
  float* pooled  = (float*)alloc((size_t)NG * 1024 * 4);
  float* scv5 = (float*)alloc(1024 * 4);
  float* shv5 = (float*)alloc(1024 * 4);
  float* scWg = (float*)alloc(1024 * 4);
  float* gconst = (float*)alloc(4);
  // single zeroed region: bns(6656) | deg(NN) | gcnt(NG) | rsum(NN)
  size_t znf = 6656 + NN + NG + NN;
  float* zbase = (float*)alloc(znf * 4);
  float* bns  = zbase;
  int*   deg  = (int*)(zbase + 6656);
  int*   gcnt = (int*)(zbase + 6656 + NN);
  float* rsum = zbase + 6656 + NN + NG;
  float* bns1 = bns;          // F=1024
  float* bns2 = bns + 2048;   // F=512
  float* bns3 = bns + 3072;   // F=256
  float* bns4 = bns + 3584;   // F=512
  float* bns5 = bns + 4608;   // F=1024

  // ---- preprocessing ----
  hipMemsetAsync(zbase, 0, znf * 4, stream);
  k_deg<<<(NTOT + 255) / 256, 256, 0, stream>>>(col, deg, batch, gcnt);
  k_pre1<<<NBLK, 256, 0, stream>>>(deg, dinv, psum);
  k_pre2<<<1, 256, 0, stream>>>(psum, pbase, gcnt, goff);
  k_pre3<<<NBLK, 256, 0, stream>>>(deg, pbase, indptr, cursor);
  k_fill<<<(NTOT + 255) / 256, 256, 0, stream>>>(row, col, dinv, cursor, csw, rsum);
  k_wconv3<<<2688, 256, 0, stream>>>(W[0], W[3], W[4], WT[0], WT[3], WT[4]);

  auto gemm = [&](const _Float16* Aop, int wl, const float* bias,
                  _Float16* Ch, float* stats, int Nn, int Kk, int relu) {
    int nbx = Nn / 128;
    if (Kk == 32)
      k_gemm16<32><<<nbx * 160, 256, 0, stream>>>(Aop, WT[wl], bias, Ch, stats, Nn, Kk, relu, nbx);
    else
      k_gemm16<64><<<nbx * 160, 256, 0, stream>>>(Aop, WT[wl], bias, Ch, stats, Nn, Kk, relu, nbx);
  };

  // ---- layer 1 (29 -> 1024): agg-first; GEMM1 fuses bias/relu/stats ----
  k_agg29<<<NN, AGG_T, 0, stream>>>(x, indptr, csw, ASM);
  gemm(ASM, 0, b[0], AH, bns1, 1024, 32, 1);                     // r1 fp16

  // ---- layer 2 (1024 -> 512): BN1 folded into W2; transform-first ----
  k_wfold<<<512, 256, 0, stream>>>(W[1], 1024, 512, bns1, g[0], be[0], WT[1], c2);
  gemm(AH, 1, nullptr, BF, nullptr, 512, 1024, 0);               // G2
  k_aggv<8, 0><<<NN / 4, 256, 0, stream>>>(BF, AH, indptr, csw, rsum, c2, b[1], nullptr); // r2
  k_stats16<<<512, 256, 0, stream>>>(AH, 512, bns2);

  // ---- layer 3 (512 -> 256): BN2 folded into W3; transform-first ----
  k_wfold<<<256, 256, 0, stream>>>(W[2], 512, 256, bns2, g[1], be[1], WT[2], c3);
  gemm(AH, 2, nullptr, BF2, nullptr, 256, 512, 0);               // G3
  k_aggv<4, 0><<<NN / 4, 256, 0, stream>>>(BF2, BF, indptr, csw, rsum, c3, b[2], nullptr); // r3
  k_stats16<<<512, 256, 0, stream>>>(BF, 256, bns3);

  // ---- layer 4 (256 -> 512): agg-first, BN3 inline in agg epilogue ----
  k_aggv<4, 1><<<NN / 4, 256, 0, stream>>>(BF, AH, indptr, csw, rsum, bns3, g[2], be[2]); // a4
  gemm(AH, 3, b[3], BF2, bns4, 512, 256, 1);                     // r4 fp16 + stats

  // ---- layer 5 (512 -> 1024): agg-first, BN4 inline; GEMM5 fp16 out ----
  k_aggv<8, 1><<<NN / 4, 256, 0, stream>>>(BF2, AH, indptr, csw, rsum, bns4, g[3], be[3]); // a5
  gemm(AH, 4, b[4], H5, bns5, 1024, 512, 1);                     // r5 fp16 + stats

  // ---- attention pooling with folded BN5 affine ----
  k_prep<<<1, 1024, 0, stream>>>(bns5, g[4], be[4], Wg, bg, scv5, shv5, scWg, gconst);
  k_gate_aff<<<NN, 256, 0, stream>>>(H5, scWg, gconst, gate);
  k_segred<<<NG, 64, 0, stream>>>(gate, goff, gmax, gsum);
  k_pool_aff<<<NG, 256, 0, stream>>>(H5, gate, goff, gmax, gsum, scv5, shv5, pooled);

  // ---- MLP head ----
  k_head<<<NG, 128, 0, stream>>>(pooled, Wf2, bf2, Wf3, bf3, Wf4, bf4, out);
}

// Round 10
// 618.076 us; speedup vs baseline: 1.2196x; 1.0459x over previous
//
#include <hip/hip_runtime.h>

#define EPS_BN 1e-5f

constexpr int NN   = 20000;       // nodes
constexpr int NE   = 320000;      // edges
constexpr int NTOT = NE + NN;     // edges + self loops
constexpr int NG   = 512;         // graphs
constexpr int MPAD = 20480;       // 160 * 128 rows
constexpr int NBLK = 79;          // ceil(NN/256)

typedef _Float16 half8  __attribute__((ext_vector_type(8)));
typedef _Float16 half2v __attribute__((ext_vector_type(2)));
typedef float floatx4   __attribute__((ext_vector_type(4)));

__device__ __forceinline__ void gload_lds16(const void* g, void* l) {
  __builtin_amdgcn_global_load_lds(
      (const __attribute__((address_space(1))) void*)g,
      (__attribute__((address_space(3))) void*)l, 16, 0, 0);
}

// ------------------------------------------------------------------
// Graph preprocessing
// ------------------------------------------------------------------
__global__ void k_deg(const int* __restrict__ col, int* __restrict__ deg,
                      const int* __restrict__ batch, int* __restrict__ gcnt) {
  int e = blockIdx.x * blockDim.x + threadIdx.x;
  if (e >= NTOT) return;
  int c = (e < NE) ? col[e] : (e - NE);
  atomicAdd(&deg[c], 1);
  if (e < NN) atomicAdd(&gcnt[batch[e]], 1);
}

// phase 1: per-block sums of deg + dinv
__global__ __launch_bounds__(256) void k_pre1(const int* __restrict__ deg,
                                              float* __restrict__ dinvv,
                                              int* __restrict__ psum) {
  __shared__ int ws[4];
  int t = threadIdx.x, lane = t & 63, wv = t >> 6;
  int idx = blockIdx.x * 256 + t;
  int d = (idx < NN) ? deg[idx] : 0;
  if (idx < NN) dinvv[idx] = rsqrtf((float)d);
  int s = d;
  for (int o = 1; o < 64; o <<= 1) { int u = __shfl_up(s, o, 64); if (lane >= o) s += u; }
  if (lane == 63) ws[wv] = s;
  __syncthreads();
  if (t == 0) psum[blockIdx.x] = ws[0] + ws[1] + ws[2] + ws[3];
}

// phase 2: scan the NBLK partials + scan gcnt (512) in one small block
__global__ __launch_bounds__(256) void k_pre2(const int* __restrict__ psum,
                                              int* __restrict__ pbase,
                                              const int* __restrict__ gcnt,
                                              int* __restrict__ goff) {
  __shared__ int ws[8];
  int t = threadIdx.x, lane = t & 63, wv = t >> 6;
  int v = (t < NBLK) ? psum[t] : 0;
  int inc = v;
  for (int o = 1; o < 64; o <<= 1) { int u = __shfl_up(inc, o, 64); if (lane >= o) inc += u; }
  if (lane == 63) ws[wv] = inc;
  __syncthreads();
  int base = 0;
  for (int w = 0; w < wv; ++w) base += ws[w];
  int excl = base + inc - v;
  if (t < NBLK) pbase[t] = excl;
  if (t == NBLK - 1) pbase[NBLK] = excl + v;
  __syncthreads();
  int a0 = gcnt[2 * t], a1 = gcnt[2 * t + 1];
  int p = a0 + a1;
  int incp = p;
  for (int o = 1; o < 64; o <<= 1) { int u = __shfl_up(incp, o, 64); if (lane >= o) incp += u; }
  if (lane == 63) ws[4 + wv] = incp;
  __syncthreads();
  int gb = 0;
  for (int w = 0; w < wv; ++w) gb += ws[4 + w];
  int exclp = gb + incp - p;
  goff[2 * t]     = exclp;
  goff[2 * t + 1] = exclp + a0;
  if (t == 255) goff[NG] = exclp + p;
}

// phase 3: emit indptr/cursor
__global__ __launch_bounds__(256) void k_pre3(const int* __restrict__ deg,
                                              const int* __restrict__ pbase,
                                              int* __restrict__ indptr,
                                              int* __restrict__ cursor) {
  __shared__ int ws[4];
  int t = threadIdx.x, lane = t & 63, wv = t >> 6;
  int idx = blockIdx.x * 256 + t;
  int d = (idx < NN) ? deg[idx] : 0;
  int inc = d;
  for (int o = 1; o < 64; o <<= 1) { int u = __shfl_up(inc, o, 64); if (lane >= o) inc += u; }
  if (lane == 63) ws[wv] = inc;
  __syncthreads();
  int base = pbase[blockIdx.x];
  for (int w = 0; w < wv; ++w) base += ws[w];
  int excl = base + inc - d;
  if (idx < NN) { indptr[idx] = excl; cursor[idx] = excl; }
  if (idx == NN - 1) indptr[NN] = excl + d;
}

// CSR fill with packed {src, w_bits} meta + rowsum
__global__ void k_fill(const int* __restrict__ row, const int* __restrict__ col,
                       const float* __restrict__ dinv, int* __restrict__ cursor,
                       int2* __restrict__ csw, float* __restrict__ rsum) {
  int e = blockIdx.x * blockDim.x + threadIdx.x;
  if (e >= NTOT) return;
  int r, c;
  if (e < NE) { r = row[e]; c = col[e]; } else { r = c = e - NE; }
  float wv = dinv[r] * dinv[c];
  int pos = atomicAdd(&cursor[c], 1);
  int2 m; m.x = r; m.y = __builtin_bit_cast(int, wv);
  csw[pos] = m;
  atomicAdd(&rsum[c], wv);
}

// ------------------------------------------------------------------
// Weight transposes (W1 pad 29->32, W4, W5) in one kernel
// ------------------------------------------------------------------
__global__ void k_wconv3(const float* __restrict__ W0, const float* __restrict__ W3,
                         const float* __restrict__ W4,
                         _Float16* __restrict__ T0, _Float16* __restrict__ T3,
                         _Float16* __restrict__ T4) {
  int idx = blockIdx.x * blockDim.x + threadIdx.x;
  if (idx < 32768) {                       // W1: K=29 (pad 32), N=1024
    int n = idx >> 5, k = idx & 31;
    T0[idx] = (_Float16)((k < 29) ? W0[(size_t)k * 1024 + n] : 0.f);
  } else if (idx < 32768 + 131072) {       // W4: K=256, N=512
    int j = idx - 32768;
    int n = j >> 8, k = j & 255;
    T3[j] = (_Float16)W3[(size_t)k * 512 + n];
  } else if (idx < 32768 + 131072 + 524288) { // W5: K=512, N=1024
    int j = idx - 163840;
    int n = j >> 9, k = j & 511;
    T4[j] = (_Float16)W4[(size_t)k * 1024 + n];
  }
}

// W' = diag(sc) W transposed to [N,K] fp16; c[n] = sum_k sh_k W[k,n]
__global__ __launch_bounds__(256) void k_wfold(const float* __restrict__ W, int K, int N,
                                               const float* __restrict__ sums,
                                               const float* __restrict__ gamma,
                                               const float* __restrict__ beta,
                                               _Float16* __restrict__ T,
                                               float* __restrict__ c) {
  __shared__ float red[256];
  int n = blockIdx.x, tid = threadIdx.x;
  const float inv_n = 1.f / NN;
  float csum = 0.f;
  for (int k = tid; k < K; k += 256) {
    float mean = sums[k] * inv_n;
    float var  = sums[K + k] * inv_n - mean * mean;
    float sc   = gamma[k] * rsqrtf(var + EPS_BN);
    float sh   = beta[k] - mean * sc;
    float wv   = W[(size_t)k * N + n];
    T[(size_t)n * K + k] = (_Float16)(sc * wv);
    csum += sh * wv;
  }
  red[tid] = csum;
  __syncthreads();
  for (int o = 128; o > 0; o >>= 1) {
    if (tid < o) red[tid] += red[tid + o];
    __syncthreads();
  }
  if (tid == 0) c[n] = red[0];
}

// ------------------------------------------------------------------
// L1 aggregation: fp32 x (F=29) -> fp16 out (stride 32).
// 4 edges per pass (116 active lanes, sub = tid/29) + 4-way LDS reduce.
// ------------------------------------------------------------------
#define AGG_CH 128
__global__ __launch_bounds__(128) void k_agg29(
    const float* __restrict__ X,
    const int* __restrict__ indptr, const int2* __restrict__ csw,
    _Float16* __restrict__ Y) {
  __shared__ int   s_src[AGG_CH];
  __shared__ float s_w[AGG_CH];
  __shared__ float red[128];
  int node = blockIdx.x;
  int tid  = threadIdx.x;
  int sub  = tid / 29;             // 0..3 for tid<116
  int feat = tid - sub * 29;
  bool act = tid < 116;
  int beg = indptr[node], end = indptr[node + 1];
  float acc = 0.f;
  for (int e0 = beg; e0 < end; e0 += AGG_CH) {
    int c = min(AGG_CH, end - e0);
    if (tid < c) {
      int2 m = csw[e0 + tid];
      s_src[tid] = m.x;
      s_w[tid]   = __builtin_bit_cast(float, m.y);
    }
    __syncthreads();
    if (act) {
      for (int j = 0; j < c; j += 4) {
        int jj = j + sub;
        if (jj < c) acc += s_w[jj] * X[(size_t)s_src[jj] * 29 + feat];
      }
    }
    __syncthreads();
  }
  red[tid] = acc;
  __syncthreads();
  if (tid < 32) {
    float v = 0.f;
    if (tid < 29) v = red[tid] + red[29 + tid] + red[58 + tid] + red[87 + tid];
    Y[(size_t)node * 32 + tid] = (_Float16)v;
  }
}

// ------------------------------------------------------------------
// Whole-row fp16 gather aggregation F=512, wave-per-node (4 nodes/block).
// MODE 0: out = relu(acc + s*p0[f] + p1[f])
// MODE 1: out = sc[f]*acc + s*sh[f]  (BN from sums p0, gamma p1, beta p2)
// ------------------------------------------------------------------
template<int MODE>
__global__ __launch_bounds__(256) void k_aggv(
    const _Float16* __restrict__ X, _Float16* __restrict__ Y,
    const int* __restrict__ indptr, const int2* __restrict__ csw,
    const float* __restrict__ rowsum,
    const float* __restrict__ p0, const float* __restrict__ p1,
    const float* __restrict__ p2)
{
  constexpr int F = 512;
  int wave = threadIdx.x >> 6;
  int lane = threadIdx.x & 63;
  int node = blockIdx.x * 4 + wave;
  int beg = indptr[node], end = indptr[node + 1];
  float acc[8];
  #pragma unroll
  for (int i = 0; i < 8; ++i) acc[i] = 0.f;
  const unsigned* Xl = (const unsigned*)X + lane * 4;

  auto body = [&](int e) {
    int2 m = csw[e];
    float we = __builtin_bit_cast(float, m.y);
    uint4 d = *(const uint4*)(Xl + (size_t)m.x * (F / 2));
    unsigned uu[4] = {d.x, d.y, d.z, d.w};
    #pragma unroll
    for (int i = 0; i < 4; ++i) {
      half2v h = __builtin_bit_cast(half2v, uu[i]);
      acc[2 * i]     = fmaf(we, (float)h[0], acc[2 * i]);
      acc[2 * i + 1] = fmaf(we, (float)h[1], acc[2 * i + 1]);
    }
  };
  int e = beg;
  for (; e + 8 <= end; e += 8) {
    body(e); body(e + 1); body(e + 2); body(e + 3);
    body(e + 4); body(e + 5); body(e + 6); body(e + 7);
  }
  for (; e < end; ++e) body(e);

  float s_n = rowsum[node];
  size_t ob = (size_t)node * F + lane * 8;
  _Float16 outv[8];
  #pragma unroll
  for (int i = 0; i < 8; ++i) {
    int f = lane * 8 + i;
    float v;
    if constexpr (MODE == 0) {
      v = fmaxf(acc[i] + s_n * p0[f] + p1[f], 0.f);
    } else {
      const float inv_n = 1.f / NN;
      float mean = p0[f] * inv_n;
      float var  = p0[F + f] * inv_n - mean * mean;
      float sc   = p1[f] * rsqrtf(var + EPS_BN);
      float sh   = p2[f] - mean * sc;
      v = sc * acc[i] + s_n * sh;
    }
    outv[i] = (_Float16)v;
  }
  *(uint4*)(Y + ob) = *(const uint4*)outv;
}

// ------------------------------------------------------------------
// Paired-node fp16 gather aggregation F=256: each wave handles TWO nodes
// (32 lanes each, 16B loads -> half the load/fma instruction count of
// the VEC=4 whole-wave variant). 8 nodes/block.
// ------------------------------------------------------------------
template<int MODE>
__global__ __launch_bounds__(256) void k_aggp(
    const _Float16* __restrict__ X, _Float16* __restrict__ Y,
    const int* __restrict__ indptr, const int2* __restrict__ csw,
    const float* __restrict__ rowsum,
    const float* __restrict__ p0, const float* __restrict__ p1,
    const float* __restrict__ p2)
{
  constexpr int F = 256;
  int wave = threadIdx.x >> 6;
  int lane = threadIdx.x & 63;
  int half = lane >> 5;
  int l32  = lane & 31;
  int node = blockIdx.x * 8 + wave * 2 + half;
  int beg = indptr[node], end = indptr[node + 1];
  int len = end - beg;
  int len0 = __shfl(len, 0, 64);
  int len1 = __shfl(len, 32, 64);
  int maxlen = max(len0, len1);

  float acc[8];
  #pragma unroll
  for (int i = 0; i < 8; ++i) acc[i] = 0.f;
  const unsigned* Xl = (const unsigned*)X + l32 * 4;   // 16B per lane

  auto body = [&](int t) {
    int e = beg + min(t, len - 1);
    int2 m = csw[e];
    float we = (t < len) ? __builtin_bit_cast(float, m.y) : 0.f;
    uint4 d = *(const uint4*)(Xl + (size_t)m.x * (F / 2));
    unsigned uu[4] = {d.x, d.y, d.z, d.w};
    #pragma unroll
    for (int i = 0; i < 4; ++i) {
      half2v h = __builtin_bit_cast(half2v, uu[i]);
      acc[2 * i]     = fmaf(we, (float)h[0], acc[2 * i]);
      acc[2 * i + 1] = fmaf(we, (float)h[1], acc[2 * i + 1]);
    }
  };
  int t = 0;
  for (; t + 4 <= maxlen; t += 4) { body(t); body(t + 1); body(t + 2); body(t + 3); }
  for (; t < maxlen; ++t) body(t);

  float s_n = rowsum[node];
  size_t ob = (size_t)node * F + l32 * 8;
  _Float16 outv[8];
  #pragma unroll
  for (int i = 0; i < 8; ++i) {
    int f = l32 * 8 + i;
    float v;
    if constexpr (MODE == 0) {
      v = fmaxf(acc[i] + s_n * p0[f] + p1[f], 0.f);
    } else {
      const float inv_n = 1.f / NN;
      float mean = p0[f] * inv_n;
      float var  = p0[F + f] * inv_n - mean * mean;
      float sc   = p1[f] * rsqrtf(var + EPS_BN);
      float sh   = p2[f] - mean * sc;
      v = sc * acc[i] + s_n * sh;
    }
    outv[i] = (_Float16)v;
  }
  *(uint4*)(Y + ob) = *(const uint4*)outv;
}

// ------------------------------------------------------------------
// fp16 MFMA GEMM, 128x128 tile, XCD-swizzled grid, XOR-swizzled LDS,
// LDS-coalesced fp16 epilogue (proven round-7/9 configuration).
// ------------------------------------------------------------------
template<int BK>
__global__ __launch_bounds__(256) void k_gemm16(
    const _Float16* __restrict__ A, const _Float16* __restrict__ B,
    const float* __restrict__ bias,
    _Float16* __restrict__ Ch,
    float* __restrict__ stats,
    int N, int K, int do_relu, int nbx)
{
  __shared__ __align__(16) union UU {
    struct { _Float16 a[128 * BK]; _Float16 b[128 * BK]; } ab;
    _Float16 c[128 * 136];
  } u;
  __shared__ float sred[256];

  const int tid  = threadIdx.x;
  const int wave = tid >> 6;
  const int lane = tid & 63;

  int lin = blockIdx.x;
  int xcd = lin & 7, seq = lin >> 3;
  int bx = seq % nbx, grp = seq / nbx;
  int by = xcd + 8 * grp;            // 0..159
  const int row0 = by * 128;
  const int col0 = bx * 128;

  const int q  = lane >> 4;
  const int mm = lane & 15;
  const int wm = wave >> 1;
  const int wn = wave & 1;

  sred[tid] = 0.f;

  constexpr int NREP = (BK == 32) ? 2 : 4;
  constexpr int RPW  = (BK == 32) ? 16 : 8;
  const _Float16* pA[NREP];
  const _Float16* pB[NREP];
  _Float16* dstA[NREP];
  _Float16* dstB[NREP];
  {
    int rl = (BK == 32) ? (lane >> 2) : (lane >> 3);
    int cp = (BK == 32) ? (lane & 3) : (lane & 7);
    #pragma unroll
    for (int rep = 0; rep < NREP; ++rep) {
      int trow = wave * 32 + rep * RPW;
      int s = (BK == 32) ? ((lane >> 3) & 3) : ((rep & 1) * 4 + (rl >> 1));
      int csrc = cp ^ s;
      pA[rep] = A + (size_t)(row0 + trow + rl) * K + csrc * 8;
      pB[rep] = B + (size_t)(col0 + trow + rl) * K + csrc * 8;
      dstA[rep] = u.ab.a + trow * BK;
      dstB[rep] = u.ab.b + trow * BK;
    }
  }

  const int sR = (BK == 32) ? ((mm >> 1) & 3) : (mm >> 1);
  int rdA[4], rdB[4];
  #pragma unroll
  for (int i = 0; i < 4; ++i) {
    rdA[i] = (wm * 64 + i * 16 + mm) * BK;
    rdB[i] = (wn * 64 + i * 16 + mm) * BK;
  }

  floatx4 acc[4][4];
  #pragma unroll
  for (int i = 0; i < 4; ++i)
    #pragma unroll
    for (int j = 0; j < 4; ++j) acc[i][j] = floatx4{0.f, 0.f, 0.f, 0.f};

  for (int k0 = 0; k0 < K; k0 += BK) {
    #pragma unroll
    for (int rep = 0; rep < NREP; ++rep) {
      gload_lds16(pA[rep], dstA[rep]);
      gload_lds16(pB[rep], dstB[rep]);
      pA[rep] += BK; pB[rep] += BK;
    }
    __syncthreads();

    #pragma unroll
    for (int kk = 0; kk < BK / 32; ++kk) {
      int pos = ((q + 4 * kk) ^ sR) * 8;
      half8 av[4];
      #pragma unroll
      for (int i = 0; i < 4; ++i) av[i] = *(const half8*)&u.ab.a[rdA[i] + pos];
      #pragma unroll
      for (int j = 0; j < 4; ++j) {
        half8 bv = *(const half8*)&u.ab.b[rdB[j] + pos];
        #pragma unroll
        for (int i = 0; i < 4; ++i)
          acc[i][j] = __builtin_amdgcn_mfma_f32_16x16x32_f16(av[i], bv, acc[i][j], 0, 0, 0);
      }
    }
    __syncthreads();
  }

  float sloc[4]  = {0.f, 0.f, 0.f, 0.f};
  float s2loc[4] = {0.f, 0.f, 0.f, 0.f};
  #pragma unroll
  for (int j = 0; j < 4; ++j) {
    int cl = wn * 64 + j * 16 + mm;
    float bv = bias ? bias[col0 + cl] : 0.f;
    #pragma unroll
    for (int i = 0; i < 4; ++i) {
      #pragma unroll
      for (int r = 0; r < 4; ++r) {
        int rl = wm * 64 + i * 16 + q * 4 + r;
        float v = acc[i][j][r] + bv;
        if (do_relu) v = fmaxf(v, 0.f);
        u.c[rl * 136 + cl] = (_Float16)v;
        if (row0 + rl < NN) { sloc[j] += v; s2loc[j] += v * v; }
      }
    }
  }

  if (stats) {
    #pragma unroll
    for (int j = 0; j < 4; ++j) {
      float a = sloc[j], b2 = s2loc[j];
      a  += __shfl_xor(a, 16, 64);  a  += __shfl_xor(a, 32, 64);
      b2 += __shfl_xor(b2, 16, 64); b2 += __shfl_xor(b2, 32, 64);
      if (q == 0) {
        int cl = wn * 64 + j * 16 + mm;
        atomicAdd(&sred[cl], a);
        atomicAdd(&sred[128 + cl], b2);
      }
    }
  }
  __syncthreads();

  #pragma unroll
  for (int pass = 0; pass < 8; ++pass) {
    int cidx = tid + pass * 256;
    int r = cidx >> 4, kc = cidx & 15;
    int rr = row0 + r;
    if (rr < NN) {
      uint4 d = *(const uint4*)&u.c[r * 136 + kc * 8];
      *(uint4*)&Ch[(size_t)rr * N + col0 + kc * 8] = d;
    }
  }

  if (stats && tid < 128) {
    atomicAdd(&stats[col0 + tid], sred[tid]);
    atomicAdd(&stats[N + col0 + tid], sred[128 + tid]);
  }
}

// ------------------------------------------------------------------
// Slim BN stats over fp16 tensor (stride == F)
// ------------------------------------------------------------------
__global__ __launch_bounds__(256) void k_stats16(const _Float16* __restrict__ X, int F,
                                                 float* __restrict__ sums) {
  int tid = threadIdx.x;
  int npf = F >> 8;
  float s[2] = {0.f, 0.f}, s2[2] = {0.f, 0.f};
  for (int r = blockIdx.x; r < NN; r += gridDim.x) {
    #pragma unroll
    for (int i = 0; i < 2; ++i) {
      if (i < npf) {
        float v = (float)X[(size_t)r * F + tid + i * 256];
        s[i] += v; s2[i] += v * v;
      }
    }
  }
  #pragma unroll
  for (int i = 0; i < 2; ++i) {
    if (i < npf) {
      atomicAdd(&sums[tid + i * 256], s[i]);
      atomicAdd(&sums[F + tid + i * 256], s2[i]);
    }
  }
}

// ------------------------------------------------------------------
// Gate with inline BN5 fold: gate[n] = sum_f sc_f Wg_f x_f + (sum_f sh_f Wg_f + bg)
// ------------------------------------------------------------------
__global__ __launch_bounds__(256) void k_gate2(const _Float16* __restrict__ X,
                                               const float* __restrict__ sums,
                                               const float* __restrict__ g5,
                                               const float* __restrict__ be5,
                                               const float* __restrict__ Wg,
                                               const float* __restrict__ bg,
                                               float* __restrict__ gate) {
  __shared__ float red[512];
  int n = blockIdx.x, tid = threadIdx.x;
  int f = tid * 4;
  const float inv_n = 1.f / NN;
  uint2 u = *(const uint2*)(X + (size_t)n * 1024 + f);
  half2v h0 = __builtin_bit_cast(half2v, u.x);
  half2v h1 = __builtin_bit_cast(half2v, u.y);
  float xv[4] = {(float)h0[0], (float)h0[1], (float)h1[0], (float)h1[1]};
  float s = 0.f, t = 0.f;
  #pragma unroll
  for (int i = 0; i < 4; ++i) {
    int ff = f + i;
    float mean = sums[ff] * inv_n;
    float var  = sums[1024 + ff] * inv_n - mean * mean;
    float sc   = g5[ff] * rsqrtf(var + EPS_BN);
    float sh   = be5[ff] - mean * sc;
    float wg   = Wg[ff];
    s += xv[i] * (sc * wg);
    t += sh * wg;
  }
  red[tid] = s;
  red[256 + tid] = t;
  __syncthreads();
  for (int o = 128; o > 0; o >>= 1) {
    if (tid < o) { red[tid] += red[tid + o]; red[256 + tid] += red[256 + tid + o]; }
    __syncthreads();
  }
  if (tid == 0) gate[n] = red[0] + red[256] + bg[0];
}

__global__ __launch_bounds__(64) void k_segred(const float* __restrict__ gate,
                                               const int* __restrict__ goff,
                                               float* __restrict__ gmax,
                                               float* __restrict__ gsum) {
  int g = blockIdx.x, tid = threadIdx.x;
  int beg = goff[g], end = goff[g + 1];
  float m = -3.4e38f;
  for (int n = beg + tid; n < end; n += 64) m = fmaxf(m, gate[n]);
  for (int o = 32; o > 0; o >>= 1) m = fmaxf(m, __shfl_down(m, o, 64));
  m = __shfl(m, 0, 64);
  float s = 0.f;
  for (int n = beg + tid; n < end; n += 64) s += expf(gate[n] - m);
  for (int o = 32; o > 0; o >>= 1) s += __shfl_down(s, o, 64);
  if (tid == 0) { gmax[g] = m; gsum[g] = s; }
}

// pool with inline BN5 fold (sum alpha = 1)
__global__ __launch_bounds__(256) void k_pool2(const _Float16* __restrict__ X,
                                               const float* __restrict__ gate,
                                               const int* __restrict__ goff,
                                               const float* __restrict__ gmax,
                                               const float* __restrict__ gsum,
                                               const float* __restrict__ sums,
                                               const float* __restrict__ g5,
                                               const float* __restrict__ be5,
                                               float* __restrict__ pooled) {
  int g = blockIdx.x, tid = threadIdx.x;
  int beg = goff[g], end = goff[g + 1];
  int f = tid * 4;
  const float inv_n = 1.f / NN;
  float acc[4] = {0.f, 0.f, 0.f, 0.f};
  bool nonempty = end > beg;
  if (nonempty) {
    float m = gmax[g], inv = 1.f / gsum[g];
    for (int n = beg; n < end; ++n) {
      float a = expf(gate[n] - m) * inv;
      uint2 u = *(const uint2*)(X + (size_t)n * 1024 + f);
      half2v h0 = __builtin_bit_cast(half2v, u.x);
      half2v h1 = __builtin_bit_cast(half2v, u.y);
      acc[0] += a * (float)h0[0];
      acc[1] += a * (float)h0[1];
      acc[2] += a * (float)h1[0];
      acc[3] += a * (float)h1[1];
    }
  }
  #pragma unroll
  for (int i = 0; i < 4; ++i) {
    int ff = f + i;
    float mean = sums[ff] * inv_n;
    float var  = sums[1024 + ff] * inv_n - mean * mean;
    float sc   = g5[ff] * rsqrtf(var + EPS_BN);
    float sh   = be5[ff] - mean * sc;
    float v = nonempty ? (acc[i] * sc + sh) : 0.f;
    pooled[(size_t)g * 1024 + ff] = v;
  }
}

// ------------------------------------------------------------------
// MLP head
// ------------------------------------------------------------------
__global__ __launch_bounds__(128) void k_head(const float* __restrict__ pooled,
                                              const float* __restrict__ Wf2, const float* __restrict__ bf2,
                                              const float* __restrict__ Wf3, const float* __restrict__ bf3,
                                              const float* __restrict__ Wf4, const float* __restrict__ bf4,
                                              float* __restrict__ out) {
  __shared__ float sp[1024];
  __shared__ float sp2[128];
  __shared__ float sp3[16];
  int g = blockIdx.x, tid = threadIdx.x;
  #pragma unroll
  for (int i = 0; i < 8; ++i) sp[tid + i * 128] = pooled[(size_t)g * 1024 + tid + i * 128];
  __syncthreads();
  float s = bf2[tid];
  for (int k = 0; k < 1024; ++k) s += sp[k] * Wf2[k * 128 + tid];
  sp2[tid] = fmaxf(s, 0.f);
  __syncthreads();
  if (tid < 16) {
    float t = bf3[tid];
    for (int k = 0; k < 128; ++k) t += sp2[k] * Wf3[k * 16 + tid];
    sp3[tid] = fmaxf(t, 0.f);
  }
  __syncthreads();
  if (tid == 0) {
    float t = bf4[0];
    for (int k = 0; k < 16; ++k) t += sp3[k] * Wf4[k];
    out[g] = t;
  }
}

// ------------------------------------------------------------------
extern "C" void kernel_launch(void* const* d_in, const int* in_sizes, int n_in,
                              void* d_out, int out_size, void* d_ws, size_t ws_size,
                              hipStream_t stream) {
  const float* x     = (const float*)d_in[0];
  const int*   ei    = (const int*)d_in[1];
  const int*   batch = (const int*)d_in[2];
  const float* W[5]; const float* b[5]; const float* g[5]; const float* be[5];
  for (int l = 0; l < 5; ++l) {
    W[l]  = (const float*)d_in[3 + 4 * l];
    b[l]  = (const float*)d_in[4 + 4 * l];
    g[l]  = (const float*)d_in[5 + 4 * l];
    be[l] = (const float*)d_in[6 + 4 * l];
  }
  const float* Wg  = (const float*)d_in[23];
  const float* bg  = (const float*)d_in[24];
  const float* Wf2 = (const float*)d_in[25];
  const float* bf2 = (const float*)d_in[26];
  const float* Wf3 = (const float*)d_in[27];
  const float* bf3 = (const float*)d_in[28];
  const float* Wf4 = (const float*)d_in[29];
  const float* bf4 = (const float*)d_in[30];
  float* out = (float*)d_out;

  const int* row = ei;
  const int* col = ei + NE;

  char* base = (char*)d_ws;
  size_t off = 0;
  auto alloc = [&](size_t bytes) -> char* {
    char* p = base + off;
    off = (off + bytes + 255) & ~(size_t)255;
    return p;
  };
  _Float16*  AH  = (_Float16*)alloc((size_t)MPAD * 1024 * 2); // GEMM A operand / r2 / a4 / a5
  _Float16*  ASM = (_Float16*)alloc((size_t)MPAD * 32 * 2);   // L1 A operand
  _Float16*  BF  = (_Float16*)alloc((size_t)NN * 512 * 2);    // gather buffer
  _Float16*  BF2 = (_Float16*)alloc((size_t)NN * 512 * 2);    // gather buffer
  _Float16*  H5  = (_Float16*)alloc((size_t)NN * 1024 * 2);   // r5 fp16
  const int wtsz[5] = {1024 * 32, 512 * 1024, 256 * 512, 512 * 256, 1024 * 512};
  _Float16* WT[5];
  for (int l = 0; l < 5; ++l) WT[l] = (_Float16*)alloc((size_t)wtsz[l] * 2);
  float* c2  = (float*)alloc(512 * 4);
  float* c3  = (float*)alloc(256 * 4);
  float* dinv    = (float*)alloc(NN * 4);
  int*   indptr  = (int*)alloc((NN + 1) * 4);
  int*   cursor  = (int*)alloc(NN * 4);
  int2*  csw     = (int2*)alloc((size_t)NTOT * 8);
  int*   psum    = (int*)alloc((NBLK + 1) * 4);
  int*   pbase   = (int*)alloc((NBLK + 1) * 4);
  int*   goff    = (int*)alloc((NG + 1) * 4);
  float* gate    = (float*)alloc(NN * 4);
  float* gmax    = (float*)alloc(NG * 4);
  float* gsum    = (float*)alloc(NG * 4);
  float* pooled  = (float*)alloc((size_t)NG * 1024 * 4);
  // single zeroed region: bns(6656) | deg(NN) | gcnt(NG) | rsum(NN)
  size_t znf = 6656 + NN + NG + NN;
  float* zbase = (float*)alloc(znf * 4);
  float* bns  = zbase;
  int*   deg  = (int*)(zbase + 6656);
  int*   gcnt = (int*)(zbase + 6656 + NN);
  float* rsum = zbase + 6656 + NN + NG;
  float* bns1 = bns;          // F=1024
  float* bns2 = bns + 2048;   // F=512
  float* bns3 = bns + 3072;   // F=256
  float* bns4 = bns + 3584;   // F=512
  float* bns5 = bns + 4608;   // F=1024

  // ---- preprocessing ----
  hipMemsetAsync(zbase, 0, znf * 4, stream);
  k_deg<<<(NTOT + 255) / 256, 256, 0, stream>>>(col, deg, batch, gcnt);
  k_pre1<<<NBLK, 256, 0, stream>>>(deg, dinv, psum);
  k_pre2<<<1, 256, 0, stream>>>(psum, pbase, gcnt, goff);
  k_pre3<<<NBLK, 256, 0, stream>>>(deg, pbase, indptr, cursor);
  k_fill<<<(NTOT + 255) / 256, 256, 0, stream>>>(row, col, dinv, cursor, csw, rsum);
  k_wconv3<<<2688, 256, 0, stream>>>(W[0], W[3], W[4], WT[0], WT[3], WT[4]);

  auto gemm = [&](const _Float16* Aop, int wl, const float* bias,
                  _Float16* Ch, float* stats, int Nn, int Kk, int relu) {
    int nbx = Nn / 128;
    if (Kk == 32)
      k_gemm16<32><<<nbx * 160, 256, 0, stream>>>(Aop, WT[wl], bias, Ch, stats, Nn, Kk, relu, nbx);
    else
      k_gemm16<64><<<nbx * 160, 256, 0, stream>>>(Aop, WT[wl], bias, Ch, stats, Nn, Kk, relu, nbx);
  };

  // ---- layer 1 (29 -> 1024): agg-first; GEMM1 fuses bias/relu/stats ----
  k_agg29<<<NN, 128, 0, stream>>>(x, indptr, csw, ASM);
  gemm(ASM, 0, b[0], AH, bns1, 1024, 32, 1);                     // r1 fp16

  // ---- layer 2 (1024 -> 512): BN1 folded into W2; transform-first ----
  k_wfold<<<512, 256, 0, stream>>>(W[1], 1024, 512, bns1, g[0], be[0], WT[1], c2);
  gemm(AH, 1, nullptr, BF, nullptr, 512, 1024, 0);               // G2
  k_aggv<0><<<NN / 4, 256, 0, stream>>>(BF, AH, indptr, csw, rsum, c2, b[1], nullptr); // r2
  k_stats16<<<512, 256, 0, stream>>>(AH, 512, bns2);

  // ---- layer 3 (512 -> 256): BN2 folded into W3; transform-first ----
  k_wfold<<<256, 256, 0, stream>>>(W[2], 512, 256, bns2, g[1], be[1], WT[2], c3);
  gemm(AH, 2, nullptr, BF2, nullptr, 256, 512, 0);               // G3
  k_aggp<0><<<NN / 8, 256, 0, stream>>>(BF2, BF, indptr, csw, rsum, c3, b[2], nullptr); // r3
  k_stats16<<<512, 256, 0, stream>>>(BF, 256, bns3);

  // ---- layer 4 (256 -> 512): agg-first, BN3 inline in agg epilogue ----
  k_aggp<1><<<NN / 8, 256, 0, stream>>>(BF, AH, indptr, csw, rsum, bns3, g[2], be[2]); // a4
  gemm(AH, 3, b[3], BF2, bns4, 512, 256, 1);                     // r4 fp16 + stats

  // ---- layer 5 (512 -> 1024): agg-first, BN4 inline; GEMM5 fp16 out ----
  k_aggv<1><<<NN / 4, 256, 0, stream>>>(BF2, AH, indptr, csw, rsum, bns4, g[3], be[3]); // a5
  gemm(AH, 4, b[4], H5, bns5, 1024, 512, 1);                     // r5 fp16 + stats

  // ---- attention pooling with inline BN5 fold ----
  k_gate2<<<NN, 256, 0, stream>>>(H5, bns5, g[4], be[4], Wg, bg, gate);
  k_segred<<<NG, 64, 0, stream>>>(gate, goff, gmax, gsum);
  k_pool2<<<NG, 256, 0, stream>>>(H5, gate, goff, gmax, gsum, bns5, g[4], be[4], pooled);

  // ---- MLP head ----
  k_head<<<NG, 128, 0, stream>>>(pooled, Wf2, bf2, Wf3, bf3, Wf4, bf4, out);
}

// Round 11
// 591.391 us; speedup vs baseline: 1.2746x; 1.0451x over previous
//
#include <hip/hip_runtime.h>

#define EPS_BN 1e-5f

constexpr int NN   = 20000;       // nodes
constexpr int NE   = 320000;      // edges
constexpr int NTOT = NE + NN;     // edges + self loops
constexpr int NG   = 512;         // graphs
constexpr int MPAD = 20480;       // 160 * 128 rows
constexpr int NBLK = 79;          // ceil(NN/256)

typedef _Float16 half8  __attribute__((ext_vector_type(8)));
typedef _Float16 half2v __attribute__((ext_vector_type(2)));
typedef float floatx4   __attribute__((ext_vector_type(4)));

__device__ __forceinline__ void gload_lds16(const void* g, void* l) {
  __builtin_amdgcn_global_load_lds(
      (const __attribute__((address_space(1))) void*)g,
      (__attribute__((address_space(3))) void*)l, 16, 0, 0);
}

// ------------------------------------------------------------------
// Graph preprocessing
// ------------------------------------------------------------------
__global__ void k_deg(const int* __restrict__ col, int* __restrict__ deg,
                      const int* __restrict__ batch, int* __restrict__ gcnt) {
  int e = blockIdx.x * blockDim.x + threadIdx.x;
  if (e >= NTOT) return;
  int c = (e < NE) ? col[e] : (e - NE);
  atomicAdd(&deg[c], 1);
  if (e < NN) atomicAdd(&gcnt[batch[e]], 1);
}

__global__ __launch_bounds__(256) void k_pre1(const int* __restrict__ deg,
                                              float* __restrict__ dinvv,
                                              int* __restrict__ psum) {
  __shared__ int ws[4];
  int t = threadIdx.x, lane = t & 63, wv = t >> 6;
  int idx = blockIdx.x * 256 + t;
  int d = (idx < NN) ? deg[idx] : 0;
  if (idx < NN) dinvv[idx] = rsqrtf((float)d);
  int s = d;
  for (int o = 1; o < 64; o <<= 1) { int u = __shfl_up(s, o, 64); if (lane >= o) s += u; }
  if (lane == 63) ws[wv] = s;
  __syncthreads();
  if (t == 0) psum[blockIdx.x] = ws[0] + ws[1] + ws[2] + ws[3];
}

__global__ __launch_bounds__(256) void k_pre2(const int* __restrict__ psum,
                                              int* __restrict__ pbase,
                                              const int* __restrict__ gcnt,
                                              int* __restrict__ goff) {
  __shared__ int ws[8];
  int t = threadIdx.x, lane = t & 63, wv = t >> 6;
  int v = (t < NBLK) ? psum[t] : 0;
  int inc = v;
  for (int o = 1; o < 64; o <<= 1) { int u = __shfl_up(inc, o, 64); if (lane >= o) inc += u; }
  if (lane == 63) ws[wv] = inc;
  __syncthreads();
  int base = 0;
  for (int w = 0; w < wv; ++w) base += ws[w];
  int excl = base + inc - v;
  if (t < NBLK) pbase[t] = excl;
  if (t == NBLK - 1) pbase[NBLK] = excl + v;
  __syncthreads();
  int a0 = gcnt[2 * t], a1 = gcnt[2 * t + 1];
  int p = a0 + a1;
  int incp = p;
  for (int o = 1; o < 64; o <<= 1) { int u = __shfl_up(incp, o, 64); if (lane >= o) incp += u; }
  if (lane == 63) ws[4 + wv] = incp;
  __syncthreads();
  int gb = 0;
  for (int w = 0; w < wv; ++w) gb += ws[4 + w];
  int exclp = gb + incp - p;
  goff[2 * t]     = exclp;
  goff[2 * t + 1] = exclp + a0;
  if (t == 255) goff[NG] = exclp + p;
}

__global__ __launch_bounds__(256) void k_pre3(const int* __restrict__ deg,
                                              const int* __restrict__ pbase,
                                              int* __restrict__ indptr,
                                              int* __restrict__ cursor) {
  __shared__ int ws[4];
  int t = threadIdx.x, lane = t & 63, wv = t >> 6;
  int idx = blockIdx.x * 256 + t;
  int d = (idx < NN) ? deg[idx] : 0;
  int inc = d;
  for (int o = 1; o < 64; o <<= 1) { int u = __shfl_up(inc, o, 64); if (lane >= o) inc += u; }
  if (lane == 63) ws[wv] = inc;
  __syncthreads();
  int base = pbase[blockIdx.x];
  for (int w = 0; w < wv; ++w) base += ws[w];
  int excl = base + inc - d;
  if (idx < NN) { indptr[idx] = excl; cursor[idx] = excl; }
  if (idx == NN - 1) indptr[NN] = excl + d;
}

__global__ void k_fill(const int* __restrict__ row, const int* __restrict__ col,
                       const float* __restrict__ dinv, int* __restrict__ cursor,
                       int2* __restrict__ csw, float* __restrict__ rsum) {
  int e = blockIdx.x * blockDim.x + threadIdx.x;
  if (e >= NTOT) return;
  int r, c;
  if (e < NE) { r = row[e]; c = col[e]; } else { r = c = e - NE; }
  float wv = dinv[r] * dinv[c];
  int pos = atomicAdd(&cursor[c], 1);
  int2 m; m.x = r; m.y = __builtin_bit_cast(int, wv);
  csw[pos] = m;
  atomicAdd(&rsum[c], wv);
}

// ------------------------------------------------------------------
// Weight transposes into MFMA FRAGMENT layout:
// frag index = ((n>>4)*(K>>5) + (k>>5))*512 + ((k>>3)&3)*128 + (n&15)*8 + (k&7)
// -> a wave's B-frag load is one contiguous, coalesced 1KB read.
// ------------------------------------------------------------------
__device__ __forceinline__ size_t fragoff(int n, int k, int kb) {
  return ((size_t)(n >> 4) * kb + (k >> 5)) * 512 + ((k >> 3) & 3) * 128 + (n & 15) * 8;
}

__global__ void k_wconv3(const float* __restrict__ W0, const float* __restrict__ W3,
                         const float* __restrict__ W4,
                         _Float16* __restrict__ T0, _Float16* __restrict__ T3,
                         _Float16* __restrict__ T4) {
  int c = blockIdx.x * blockDim.x + threadIdx.x;   // 16B chunk index
  _Float16 ov[8];
  if (c < 4096) {                                  // W1: N=1024, Kp=32 (K=29)
    int n = c >> 2, k = (c & 3) * 8;
    #pragma unroll
    for (int i = 0; i < 8; ++i)
      ov[i] = (_Float16)((k + i < 29) ? W0[(size_t)(k + i) * 1024 + n] : 0.f);
    *(uint4*)&T0[fragoff(n, k, 1)] = *(const uint4*)ov;
  } else if (c < 4096 + 16384) {                   // W4: N=512, K=256
    int c2 = c - 4096;
    int n = c2 >> 5, k = (c2 & 31) * 8;
    #pragma unroll
    for (int i = 0; i < 8; ++i)
      ov[i] = (_Float16)W3[(size_t)(k + i) * 512 + n];
    *(uint4*)&T3[fragoff(n, k, 8)] = *(const uint4*)ov;
  } else if (c < 4096 + 16384 + 65536) {           // W5: N=1024, K=512
    int c3 = c - 20480;
    int n = c3 >> 6, k = (c3 & 63) * 8;
    #pragma unroll
    for (int i = 0; i < 8; ++i)
      ov[i] = (_Float16)W4[(size_t)(k + i) * 1024 + n];
    *(uint4*)&T4[fragoff(n, k, 16)] = *(const uint4*)ov;
  }
}

// W' = diag(sc) W -> fragment layout fp16; c[n] = sum_k sh_k W[k,n]
__global__ __launch_bounds__(256) void k_wfold(const float* __restrict__ W, int K, int N,
                                               const float* __restrict__ sums,
                                               const float* __restrict__ gamma,
                                               const float* __restrict__ beta,
                                               _Float16* __restrict__ T,
                                               float* __restrict__ c) {
  __shared__ float red[256];
  int n = blockIdx.x, tid = threadIdx.x;
  int kb = K >> 5;
  const float inv_n = 1.f / NN;
  float csum = 0.f;
  for (int kc = tid; kc < (K >> 3); kc += 256) {
    int k = kc * 8;
    _Float16 ov[8];
    #pragma unroll
    for (int i = 0; i < 8; ++i) {
      int ki = k + i;
      float mean = sums[ki] * inv_n;
      float var  = sums[K + ki] * inv_n - mean * mean;
      float sc   = gamma[ki] * rsqrtf(var + EPS_BN);
      float sh   = beta[ki] - mean * sc;
      float wv   = W[(size_t)ki * N + n];
      ov[i] = (_Float16)(sc * wv);
      csum += sh * wv;
    }
    *(uint4*)&T[fragoff(n, k, kb)] = *(const uint4*)ov;
  }
  red[tid] = csum;
  __syncthreads();
  for (int o = 128; o > 0; o >>= 1) {
    if (tid < o) red[tid] += red[tid + o];
    __syncthreads();
  }
  if (tid == 0) c[n] = red[0];
}

// ------------------------------------------------------------------
// L1 aggregation: fp32 x (F=29) -> fp16 out (stride 32).
// ------------------------------------------------------------------
#define AGG_CH 128
__global__ __launch_bounds__(128) void k_agg29(
    const float* __restrict__ X,
    const int* __restrict__ indptr, const int2* __restrict__ csw,
    _Float16* __restrict__ Y) {
  __shared__ int   s_src[AGG_CH];
  __shared__ float s_w[AGG_CH];
  __shared__ float red[128];
  int node = blockIdx.x;
  int tid  = threadIdx.x;
  int sub  = tid / 29;
  int feat = tid - sub * 29;
  bool act = tid < 116;
  int beg = indptr[node], end = indptr[node + 1];
  float acc = 0.f;
  for (int e0 = beg; e0 < end; e0 += AGG_CH) {
    int c = min(AGG_CH, end - e0);
    if (tid < c) {
      int2 m = csw[e0 + tid];
      s_src[tid] = m.x;
      s_w[tid]   = __builtin_bit_cast(float, m.y);
    }
    __syncthreads();
    if (act) {
      for (int j = 0; j < c; j += 4) {
        int jj = j + sub;
        if (jj < c) acc += s_w[jj] * X[(size_t)s_src[jj] * 29 + feat];
      }
    }
    __syncthreads();
  }
  red[tid] = acc;
  __syncthreads();
  if (tid < 32) {
    float v = 0.f;
    if (tid < 29) v = red[tid] + red[29 + tid] + red[58 + tid] + red[87 + tid];
    Y[(size_t)node * 32 + tid] = (_Float16)v;
  }
}

// ------------------------------------------------------------------
// Whole-row fp16 gather aggregation F=512, wave-per-node (4 nodes/block).
// ------------------------------------------------------------------
template<int MODE>
__global__ __launch_bounds__(256) void k_aggv(
    const _Float16* __restrict__ X, _Float16* __restrict__ Y,
    const int* __restrict__ indptr, const int2* __restrict__ csw,
    const float* __restrict__ rowsum,
    const float* __restrict__ p0, const float* __restrict__ p1,
    const float* __restrict__ p2)
{
  constexpr int F = 512;
  int wave = threadIdx.x >> 6;
  int lane = threadIdx.x & 63;
  int node = blockIdx.x * 4 + wave;
  int beg = indptr[node], end = indptr[node + 1];
  float acc[8];
  #pragma unroll
  for (int i = 0; i < 8; ++i) acc[i] = 0.f;
  const unsigned* Xl = (const unsigned*)X + lane * 4;

  auto body = [&](int e) {
    int2 m = csw[e];
    float we = __builtin_bit_cast(float, m.y);
    uint4 d = *(const uint4*)(Xl + (size_t)m.x * (F / 2));
    unsigned uu[4] = {d.x, d.y, d.z, d.w};
    #pragma unroll
    for (int i = 0; i < 4; ++i) {
      half2v h = __builtin_bit_cast(half2v, uu[i]);
      acc[2 * i]     = fmaf(we, (float)h[0], acc[2 * i]);
      acc[2 * i + 1] = fmaf(we, (float)h[1], acc[2 * i + 1]);
    }
  };
  int e = beg;
  for (; e + 8 <= end; e += 8) {
    body(e); body(e + 1); body(e + 2); body(e + 3);
    body(e + 4); body(e + 5); body(e + 6); body(e + 7);
  }
  for (; e < end; ++e) body(e);

  float s_n = rowsum[node];
  size_t ob = (size_t)node * F + lane * 8;
  _Float16 outv[8];
  #pragma unroll
  for (int i = 0; i < 8; ++i) {
    int f = lane * 8 + i;
    float v;
    if constexpr (MODE == 0) {
      v = fmaxf(acc[i] + s_n * p0[f] + p1[f], 0.f);
    } else {
      const float inv_n = 1.f / NN;
      float mean = p0[f] * inv_n;
      float var  = p0[F + f] * inv_n - mean * mean;
      float sc   = p1[f] * rsqrtf(var + EPS_BN);
      float sh   = p2[f] - mean * sc;
      v = sc * acc[i] + s_n * sh;
    }
    outv[i] = (_Float16)v;
  }
  *(uint4*)(Y + ob) = *(const uint4*)outv;
}

// ------------------------------------------------------------------
// Paired-node fp16 gather aggregation F=256 (2 nodes/wave, 16B loads).
// ------------------------------------------------------------------
template<int MODE>
__global__ __launch_bounds__(256) void k_aggp(
    const _Float16* __restrict__ X, _Float16* __restrict__ Y,
    const int* __restrict__ indptr, const int2* __restrict__ csw,
    const float* __restrict__ rowsum,
    const float* __restrict__ p0, const float* __restrict__ p1,
    const float* __restrict__ p2)
{
  constexpr int F = 256;
  int wave = threadIdx.x >> 6;
  int lane = threadIdx.x & 63;
  int half = lane >> 5;
  int l32  = lane & 31;
  int node = blockIdx.x * 8 + wave * 2 + half;
  int beg = indptr[node], end = indptr[node + 1];
  int len = end - beg;
  int len0 = __shfl(len, 0, 64);
  int len1 = __shfl(len, 32, 64);
  int maxlen = max(len0, len1);

  float acc[8];
  #pragma unroll
  for (int i = 0; i < 8; ++i) acc[i] = 0.f;
  const unsigned* Xl = (const unsigned*)X + l32 * 4;

  auto body = [&](int t) {
    int e = beg + min(t, len - 1);
    int2 m = csw[e];
    float we = (t < len) ? __builtin_bit_cast(float, m.y) : 0.f;
    uint4 d = *(const uint4*)(Xl + (size_t)m.x * (F / 2));
    unsigned uu[4] = {d.x, d.y, d.z, d.w};
    #pragma unroll
    for (int i = 0; i < 4; ++i) {
      half2v h = __builtin_bit_cast(half2v, uu[i]);
      acc[2 * i]     = fmaf(we, (float)h[0], acc[2 * i]);
      acc[2 * i + 1] = fmaf(we, (float)h[1], acc[2 * i + 1]);
    }
  };
  int t = 0;
  for (; t + 4 <= maxlen; t += 4) { body(t); body(t + 1); body(t + 2); body(t + 3); }
  for (; t < maxlen; ++t) body(t);

  float s_n = rowsum[node];
  size_t ob = (size_t)node * F + l32 * 8;
  _Float16 outv[8];
  #pragma unroll
  for (int i = 0; i < 8; ++i) {
    int f = l32 * 8 + i;
    float v;
    if constexpr (MODE == 0) {
      v = fmaxf(acc[i] + s_n * p0[f] + p1[f], 0.f);
    } else {
      const float inv_n = 1.f / NN;
      float mean = p0[f] * inv_n;
      float var  = p0[F + f] * inv_n - mean * mean;
      float sc   = p1[f] * rsqrtf(var + EPS_BN);
      float sh   = p2[f] - mean * sc;
      v = sc * acc[i] + s_n * sh;
    }
    outv[i] = (_Float16)v;
  }
  *(uint4*)(Y + ob) = *(const uint4*)outv;
}

// ------------------------------------------------------------------
// fp16 MFMA GEMM: A async-staged in LDS (XOR swizzle); B read directly
// from global in FRAGMENT layout (coalesced 1KB/load, L1/L2-hot) ->
// LDS traffic halves vs staging both. LDS-coalesced fp16 C epilogue.
// ------------------------------------------------------------------
template<int BK>
__global__ __launch_bounds__(256) void k_gemm16(
    const _Float16* __restrict__ A, const _Float16* __restrict__ Bf,
    const float* __restrict__ bias,
    _Float16* __restrict__ Ch,
    float* __restrict__ stats,
    int N, int K, int do_relu, int nbx)
{
  __shared__ __align__(16) union UU {
    _Float16 a[128 * BK];
    _Float16 c[128 * 136];
  } u;
  __shared__ float sred[256];

  const int tid  = threadIdx.x;
  const int wave = tid >> 6;
  const int lane = tid & 63;

  int lin = blockIdx.x;
  int xcd = lin & 7, seq = lin >> 3;
  int bx = seq % nbx, grp = seq / nbx;
  int by = xcd + 8 * grp;            // 0..159
  const int row0 = by * 128;
  const int col0 = bx * 128;

  const int q  = lane >> 4;
  const int mm = lane & 15;
  const int wm = wave >> 1;
  const int wn = wave & 1;

  sred[tid] = 0.f;

  constexpr int NREP = (BK == 32) ? 2 : 4;
  constexpr int RPW  = (BK == 32) ? 16 : 8;
  const _Float16* pA[NREP];
  _Float16* dstA[NREP];
  {
    int rl = (BK == 32) ? (lane >> 2) : (lane >> 3);
    int cp = (BK == 32) ? (lane & 3) : (lane & 7);
    #pragma unroll
    for (int rep = 0; rep < NREP; ++rep) {
      int trow = wave * 32 + rep * RPW;
      int s = (BK == 32) ? ((lane >> 3) & 3) : ((rep & 1) * 4 + (rl >> 1));
      int csrc = cp ^ s;
      pA[rep] = A + (size_t)(row0 + trow + rl) * K + csrc * 8;
      dstA[rep] = u.a + trow * BK;
    }
  }

  const int sR = (BK == 32) ? ((mm >> 1) & 3) : (mm >> 1);
  int rdA[4];
  #pragma unroll
  for (int i = 0; i < 4; ++i) rdA[i] = (wm * 64 + i * 16 + mm) * BK;

  // B fragment pointers (global, fragment-ordered)
  const int kb = K >> 5;
  const _Float16* pb[4];
  #pragma unroll
  for (int j = 0; j < 4; ++j)
    pb[j] = Bf + (size_t)((col0 + wn * 64 + j * 16) >> 4) * kb * 512 + lane * 8;

  floatx4 acc[4][4];
  #pragma unroll
  for (int i = 0; i < 4; ++i)
    #pragma unroll
    for (int j = 0; j < 4; ++j) acc[i][j] = floatx4{0.f, 0.f, 0.f, 0.f};

  for (int k0 = 0; k0 < K; k0 += BK) {
    #pragma unroll
    for (int rep = 0; rep < NREP; ++rep) {
      gload_lds16(pA[rep], dstA[rep]);
      pA[rep] += BK;
    }
    __syncthreads();

    #pragma unroll
    for (int kk = 0; kk < BK / 32; ++kk) {
      half8 bv[4];
      #pragma unroll
      for (int j = 0; j < 4; ++j) { bv[j] = *(const half8*)pb[j]; pb[j] += 512; }
      int pos = ((q + 4 * kk) ^ sR) * 8;
      half8 av[4];
      #pragma unroll
      for (int i = 0; i < 4; ++i) av[i] = *(const half8*)&u.a[rdA[i] + pos];
      #pragma unroll
      for (int j = 0; j < 4; ++j)
        #pragma unroll
        for (int i = 0; i < 4; ++i)
          acc[i][j] = __builtin_amdgcn_mfma_f32_16x16x32_f16(av[i], bv[j], acc[i][j], 0, 0, 0);
    }
    __syncthreads();
  }

  float sloc[4]  = {0.f, 0.f, 0.f, 0.f};
  float s2loc[4] = {0.f, 0.f, 0.f, 0.f};
  #pragma unroll
  for (int j = 0; j < 4; ++j) {
    int cl = wn * 64 + j * 16 + mm;
    float bv = bias ? bias[col0 + cl] : 0.f;
    #pragma unroll
    for (int i = 0; i < 4; ++i) {
      #pragma unroll
      for (int r = 0; r < 4; ++r) {
        int rl = wm * 64 + i * 16 + q * 4 + r;
        float v = acc[i][j][r] + bv;
        if (do_relu) v = fmaxf(v, 0.f);
        u.c[rl * 136 + cl] = (_Float16)v;
        if (row0 + rl < NN) { sloc[j] += v; s2loc[j] += v * v; }
      }
    }
  }

  if (stats) {
    #pragma unroll
    for (int j = 0; j < 4; ++j) {
      float a = sloc[j], b2 = s2loc[j];
      a  += __shfl_xor(a, 16, 64);  a  += __shfl_xor(a, 32, 64);
      b2 += __shfl_xor(b2, 16, 64); b2 += __shfl_xor(b2, 32, 64);
      if (q == 0) {
        int cl = wn * 64 + j * 16 + mm;
        atomicAdd(&sred[cl], a);
        atomicAdd(&sred[128 + cl], b2);
      }
    }
  }
  __syncthreads();

  #pragma unroll
  for (int pass = 0; pass < 8; ++pass) {
    int cidx = tid + pass * 256;
    int r = cidx >> 4, kc = cidx & 15;
    int rr = row0 + r;
    if (rr < NN) {
      uint4 d = *(const uint4*)&u.c[r * 136 + kc * 8];
      *(uint4*)&Ch[(size_t)rr * N + col0 + kc * 8] = d;
    }
  }

  if (stats && tid < 128) {
    atomicAdd(&stats[col0 + tid], sred[tid]);
    atomicAdd(&stats[N + col0 + tid], sred[128 + tid]);
  }
}

// ------------------------------------------------------------------
// Slim BN stats over fp16 tensor (stride == F)
// ------------------------------------------------------------------
__global__ __launch_bounds__(256) void k_stats16(const _Float16* __restrict__ X, int F,
                                                 float* __restrict__ sums) {
  int tid = threadIdx.x;
  int npf = F >> 8;
  float s[2] = {0.f, 0.f}, s2[2] = {0.f, 0.f};
  for (int r = blockIdx.x; r < NN; r += gridDim.x) {
    #pragma unroll
    for (int i = 0; i < 2; ++i) {
      if (i < npf) {
        float v = (float)X[(size_t)r * F + tid + i * 256];
        s[i] += v; s2[i] += v * v;
      }
    }
  }
  #pragma unroll
  for (int i = 0; i < 2; ++i) {
    if (i < npf) {
      atomicAdd(&sums[tid + i * 256], s[i]);
      atomicAdd(&sums[F + tid + i * 256], s2[i]);
    }
  }
}

// ------------------------------------------------------------------
// Gate with inline BN5 fold
// ------------------------------------------------------------------
__global__ __launch_bounds__(256) void k_gate2(const _Float16* __restrict__ X,
                                               const float* __restrict__ sums,
                                               const float* __restrict__ g5,
                                               const float* __restrict__ be5,
                                               const float* __restrict__ Wg,
                                               const float* __restrict__ bg,
                                               float* __restrict__ gate) {
  __shared__ float red[512];
  int n = blockIdx.x, tid = threadIdx.x;
  int f = tid * 4;
  const float inv_n = 1.f / NN;
  uint2 u = *(const uint2*)(X + (size_t)n * 1024 + f);
  half2v h0 = __builtin_bit_cast(half2v, u.x);
  half2v h1 = __builtin_bit_cast(half2v, u.y);
  float xv[4] = {(float)h0[0], (float)h0[1], (float)h1[0], (float)h1[1]};
  float s = 0.f, t = 0.f;
  #pragma unroll
  for (int i = 0; i < 4; ++i) {
    int ff = f + i;
    float mean = sums[ff] * inv_n;
    float var  = sums[1024 + ff] * inv_n - mean * mean;
    float sc   = g5[ff] * rsqrtf(var + EPS_BN);
    float sh   = be5[ff] - mean * sc;
    float wg   = Wg[ff];
    s += xv[i] * (sc * wg);
    t += sh * wg;
  }
  red[tid] = s;
  red[256 + tid] = t;
  __syncthreads();
  for (int o = 128; o > 0; o >>= 1) {
    if (tid < o) { red[tid] += red[tid + o]; red[256 + tid] += red[256 + tid + o]; }
    __syncthreads();
  }
  if (tid == 0) gate[n] = red[0] + red[256] + bg[0];
}

// ------------------------------------------------------------------
// Fused segred + pool (BN5 fold, pooled stays in LDS) + MLP head
// ------------------------------------------------------------------
__global__ __launch_bounds__(256) void k_poolhead(
    const _Float16* __restrict__ X, const float* __restrict__ gate,
    const int* __restrict__ goff,
    const float* __restrict__ sums, const float* __restrict__ g5,
    const float* __restrict__ be5,
    const float* __restrict__ Wf2, const float* __restrict__ bf2,
    const float* __restrict__ Wf3, const float* __restrict__ bf3,
    const float* __restrict__ Wf4, const float* __restrict__ bf4,
    float* __restrict__ out)
{
  __shared__ float red[256];
  __shared__ float sp[1024];
  __shared__ float sp2[128];
  __shared__ float sp3[16];
  int g = blockIdx.x, tid = threadIdx.x;
  int beg = goff[g], end = goff[g + 1];
  bool nonempty = end > beg;

  // segred: max
  float m = -3.4e38f;
  for (int n = beg + tid; n < end; n += 256) m = fmaxf(m, gate[n]);
  red[tid] = m;
  __syncthreads();
  for (int o = 128; o > 0; o >>= 1) {
    if (tid < o) red[tid] = fmaxf(red[tid], red[tid + o]);
    __syncthreads();
  }
  m = red[0];
  __syncthreads();
  // segred: sum of exp
  float s = 0.f;
  for (int n = beg + tid; n < end; n += 256) s += expf(gate[n] - m);
  red[tid] = s;
  __syncthreads();
  for (int o = 128; o > 0; o >>= 1) {
    if (tid < o) red[tid] += red[tid + o];
    __syncthreads();
  }
  float inv = nonempty ? (1.f / red[0]) : 0.f;

  // pool with BN5 fold -> LDS
  int f = tid * 4;
  const float inv_n = 1.f / NN;
  float acc[4] = {0.f, 0.f, 0.f, 0.f};
  if (nonempty) {
    for (int n = beg; n < end; ++n) {
      float a = expf(gate[n] - m) * inv;
      uint2 u = *(const uint2*)(X + (size_t)n * 1024 + f);
      half2v h0 = __builtin_bit_cast(half2v, u.x);
      half2v h1 = __builtin_bit_cast(half2v, u.y);
      acc[0] += a * (float)h0[0];
      acc[1] += a * (float)h0[1];
      acc[2] += a * (float)h1[0];
      acc[3] += a * (float)h1[1];
    }
  }
  #pragma unroll
  for (int i = 0; i < 4; ++i) {
    int ff = f + i;
    float mean = sums[ff] * inv_n;
    float var  = sums[1024 + ff] * inv_n - mean * mean;
    float sc   = g5[ff] * rsqrtf(var + EPS_BN);
    float sh   = be5[ff] - mean * sc;
    sp[ff] = nonempty ? (acc[i] * sc + sh) : 0.f;
  }
  __syncthreads();

  // head
  if (tid < 128) {
    float s2 = bf2[tid];
    for (int k = 0; k < 1024; ++k) s2 += sp[k] * Wf2[k * 128 + tid];
    sp2[tid] = fmaxf(s2, 0.f);
  }
  __syncthreads();
  if (tid < 16) {
    float t = bf3[tid];
    for (int k = 0; k < 128; ++k) t += sp2[k] * Wf3[k * 16 + tid];
    sp3[tid] = fmaxf(t, 0.f);
  }
  __syncthreads();
  if (tid == 0) {
    float t = bf4[0];
    for (int k = 0; k < 16; ++k) t += sp3[k] * Wf4[k];
    out[g] = t;
  }
}

// ------------------------------------------------------------------
extern "C" void kernel_launch(void* const* d_in, const int* in_sizes, int n_in,
                              void* d_out, int out_size, void* d_ws, size_t ws_size,
                              hipStream_t stream) {
  const float* x     = (const float*)d_in[0];
  const int*   ei    = (const int*)d_in[1];
  const int*   batch = (const int*)d_in[2];
  const float* W[5]; const float* b[5]; const float* g[5]; const float* be[5];
  for (int l = 0; l < 5; ++l) {
    W[l]  = (const float*)d_in[3 + 4 * l];
    b[l]  = (const float*)d_in[4 + 4 * l];
    g[l]  = (const float*)d_in[5 + 4 * l];
    be[l] = (const float*)d_in[6 + 4 * l];
  }
  const float* Wg  = (const float*)d_in[23];
  const float* bg  = (const float*)d_in[24];
  const float* Wf2 = (const float*)d_in[25];
  const float* bf2 = (const float*)d_in[26];
  const float* Wf3 = (const float*)d_in[27];
  const float* bf3 = (const float*)d_in[28];
  const float* Wf4 = (const float*)d_in[29];
  const float* bf4 = (const float*)d_in[30];
  float* out = (float*)d_out;

  const int* row = ei;
  const int* col = ei + NE;

  char* base = (char*)d_ws;
  size_t off = 0;
  auto alloc = [&](size_t bytes) -> char* {
    char* p = base + off;
    off = (off + bytes + 255) & ~(size_t)255;
    return p;
  };
  _Float16*  AH  = (_Float16*)alloc((size_t)MPAD * 1024 * 2);
  _Float16*  ASM = (_Float16*)alloc((size_t)MPAD * 32 * 2);
  _Float16*  BF  = (_Float16*)alloc((size_t)NN * 512 * 2);
  _Float16*  BF2 = (_Float16*)alloc((size_t)NN * 512 * 2);
  _Float16*  H5  = (_Float16*)alloc((size_t)NN * 1024 * 2);
  const int wtsz[5] = {1024 * 32, 512 * 1024, 256 * 512, 512 * 256, 1024 * 512};
  _Float16* WT[5];
  for (int l = 0; l < 5; ++l) WT[l] = (_Float16*)alloc((size_t)wtsz[l] * 2);
  float* c2  = (float*)alloc(512 * 4);
  float* c3  = (float*)alloc(256 * 4);
  float* dinv    = (float*)alloc(NN * 4);
  int*   indptr  = (int*)alloc((NN + 1) * 4);
  int*   cursor  = (int*)alloc(NN * 4);
  int2*  csw     = (int2*)alloc((size_t)NTOT * 8);
  int*   psum    = (int*)alloc((NBLK + 1) * 4);
  int*   pbase   = (int*)alloc((NBLK + 1) * 4);
  int*   goff    = (int*)alloc((NG + 1) * 4);
  float* gate    = (float*)alloc(NN * 4);
  size_t znf = 6656 + NN + NG + NN;
  float* zbase = (float*)alloc(znf * 4);
  float* bns  = zbase;
  int*   deg  = (int*)(zbase + 6656);
  int*   gcnt = (int*)(zbase + 6656 + NN);
  float* rsum = zbase + 6656 + NN + NG;
  float* bns1 = bns;          // F=1024
  float* bns2 = bns + 2048;   // F=512
  float* bns3 = bns + 3072;   // F=256
  float* bns4 = bns + 3584;   // F=512
  float* bns5 = bns + 4608;   // F=1024

  // ---- preprocessing ----
  hipMemsetAsync(zbase, 0, znf * 4, stream);
  k_deg<<<(NTOT + 255) / 256, 256, 0, stream>>>(col, deg, batch, gcnt);
  k_pre1<<<NBLK, 256, 0, stream>>>(deg, dinv, psum);
  k_pre2<<<1, 256, 0, stream>>>(psum, pbase, gcnt, goff);
  k_pre3<<<NBLK, 256, 0, stream>>>(deg, pbase, indptr, cursor);
  k_fill<<<(NTOT + 255) / 256, 256, 0, stream>>>(row, col, dinv, cursor, csw, rsum);
  k_wconv3<<<336, 256, 0, stream>>>(W[0], W[3], W[4], WT[0], WT[3], WT[4]);

  auto gemm = [&](const _Float16* Aop, int wl, const float* bias,
                  _Float16* Ch, float* stats, int Nn, int Kk, int relu) {
    int nbx = Nn / 128;
    if (Kk == 32)
      k_gemm16<32><<<nbx * 160, 256, 0, stream>>>(Aop, WT[wl], bias, Ch, stats, Nn, Kk, relu, nbx);
    else
      k_gemm16<64><<<nbx * 160, 256, 0, stream>>>(Aop, WT[wl], bias, Ch, stats, Nn, Kk, relu, nbx);
  };

  // ---- layer 1 (29 -> 1024): agg-first; GEMM1 fuses bias/relu/stats ----
  k_agg29<<<NN, 128, 0, stream>>>(x, indptr, csw, ASM);
  gemm(ASM, 0, b[0], AH, bns1, 1024, 32, 1);                     // r1 fp16

  // ---- layer 2 (1024 -> 512): BN1 folded into W2; transform-first ----
  k_wfold<<<512, 256, 0, stream>>>(W[1], 1024, 512, bns1, g[0], be[0], WT[1], c2);
  gemm(AH, 1, nullptr, BF, nullptr, 512, 1024, 0);               // G2
  k_aggv<0><<<NN / 4, 256, 0, stream>>>(BF, AH, indptr, csw, rsum, c2, b[1], nullptr); // r2
  k_stats16<<<512, 256, 0, stream>>>(AH, 512, bns2);

  // ---- layer 3 (512 -> 256): BN2 folded into W3; transform-first ----
  k_wfold<<<256, 256, 0, stream>>>(W[2], 512, 256, bns2, g[1], be[1], WT[2], c3);
  gemm(AH, 2, nullptr, BF2, nullptr, 256, 512, 0);               // G3
  k_aggp<0><<<NN / 8, 256, 0, stream>>>(BF2, BF, indptr, csw, rsum, c3, b[2], nullptr); // r3
  k_stats16<<<512, 256, 0, stream>>>(BF, 256, bns3);

  // ---- layer 4 (256 -> 512): agg-first, BN3 inline in agg epilogue ----
  k_aggp<1><<<NN / 8, 256, 0, stream>>>(BF, AH, indptr, csw, rsum, bns3, g[2], be[2]); // a4
  gemm(AH, 3, b[3], BF2, bns4, 512, 256, 1);                     // r4 fp16 + stats

  // ---- layer 5 (512 -> 1024): agg-first, BN4 inline; GEMM5 fp16 out ----
  k_aggv<1><<<NN / 4, 256, 0, stream>>>(BF2, AH, indptr, csw, rsum, bns4, g[3], be[3]); // a5
  gemm(AH, 4, b[4], H5, bns5, 1024, 512, 1);                     // r5 fp16 + stats

  // ---- attention pooling (inline BN5 fold) + head ----
  k_gate2<<<NN, 256, 0, stream>>>(H5, bns5, g[4], be[4], Wg, bg, gate);
  k_poolhead<<<NG, 256, 0, stream>>>(H5, gate, goff, bns5, g[4], be[4],
                                     Wf2, bf2, Wf3, bf3, Wf4, bf4, out);
}

// Round 12
// 590.345 us; speedup vs baseline: 1.2769x; 1.0018x over previous
//
#include <hip/hip_runtime.h>

#define EPS_BN 1e-5f

constexpr int NN   = 20000;       // nodes
constexpr int NE   = 320000;      // edges
constexpr int NTOT = NE + NN;     // edges + self loops
constexpr int NG   = 512;         // graphs
constexpr int MPAD = 20480;       // 160 * 128 rows
constexpr int NBLK = 79;          // ceil(NN/256)

typedef _Float16 half8  __attribute__((ext_vector_type(8)));
typedef _Float16 half2v __attribute__((ext_vector_type(2)));
typedef float floatx4   __attribute__((ext_vector_type(4)));

__device__ __forceinline__ void gload_lds16(const void* g, void* l) {
  __builtin_amdgcn_global_load_lds(
      (const __attribute__((address_space(1))) void*)g,
      (__attribute__((address_space(3))) void*)l, 16, 0, 0);
}

// ------------------------------------------------------------------
// Graph preprocessing
// ------------------------------------------------------------------
__global__ void k_deg(const int* __restrict__ col, int* __restrict__ deg,
                      const int* __restrict__ batch, int* __restrict__ gcnt) {
  int e = blockIdx.x * blockDim.x + threadIdx.x;
  if (e >= NTOT) return;
  int c = (e < NE) ? col[e] : (e - NE);
  atomicAdd(&deg[c], 1);
  if (e < NN) atomicAdd(&gcnt[batch[e]], 1);
}

__global__ __launch_bounds__(256) void k_pre1(const int* __restrict__ deg,
                                              float* __restrict__ dinvv,
                                              int* __restrict__ psum) {
  __shared__ int ws[4];
  int t = threadIdx.x, lane = t & 63, wv = t >> 6;
  int idx = blockIdx.x * 256 + t;
  int d = (idx < NN) ? deg[idx] : 0;
  if (idx < NN) dinvv[idx] = rsqrtf((float)d);
  int s = d;
  for (int o = 1; o < 64; o <<= 1) { int u = __shfl_up(s, o, 64); if (lane >= o) s += u; }
  if (lane == 63) ws[wv] = s;
  __syncthreads();
  if (t == 0) psum[blockIdx.x] = ws[0] + ws[1] + ws[2] + ws[3];
}

__global__ __launch_bounds__(256) void k_pre2(const int* __restrict__ psum,
                                              int* __restrict__ pbase,
                                              const int* __restrict__ gcnt,
                                              int* __restrict__ goff) {
  __shared__ int ws[8];
  int t = threadIdx.x, lane = t & 63, wv = t >> 6;
  int v = (t < NBLK) ? psum[t] : 0;
  int inc = v;
  for (int o = 1; o < 64; o <<= 1) { int u = __shfl_up(inc, o, 64); if (lane >= o) inc += u; }
  if (lane == 63) ws[wv] = inc;
  __syncthreads();
  int base = 0;
  for (int w = 0; w < wv; ++w) base += ws[w];
  int excl = base + inc - v;
  if (t < NBLK) pbase[t] = excl;
  if (t == NBLK - 1) pbase[NBLK] = excl + v;
  __syncthreads();
  int a0 = gcnt[2 * t], a1 = gcnt[2 * t + 1];
  int p = a0 + a1;
  int incp = p;
  for (int o = 1; o < 64; o <<= 1) { int u = __shfl_up(incp, o, 64); if (lane >= o) incp += u; }
  if (lane == 63) ws[4 + wv] = incp;
  __syncthreads();
  int gb = 0;
  for (int w = 0; w < wv; ++w) gb += ws[4 + w];
  int exclp = gb + incp - p;
  goff[2 * t]     = exclp;
  goff[2 * t + 1] = exclp + a0;
  if (t == 255) goff[NG] = exclp + p;
}

__global__ __launch_bounds__(256) void k_pre3(const int* __restrict__ deg,
                                              const int* __restrict__ pbase,
                                              int* __restrict__ indptr,
                                              int* __restrict__ cursor) {
  __shared__ int ws[4];
  int t = threadIdx.x, lane = t & 63, wv = t >> 6;
  int idx = blockIdx.x * 256 + t;
  int d = (idx < NN) ? deg[idx] : 0;
  int inc = d;
  for (int o = 1; o < 64; o <<= 1) { int u = __shfl_up(inc, o, 64); if (lane >= o) inc += u; }
  if (lane == 63) ws[wv] = inc;
  __syncthreads();
  int base = pbase[blockIdx.x];
  for (int w = 0; w < wv; ++w) base += ws[w];
  int excl = base + inc - d;
  if (idx < NN) { indptr[idx] = excl; cursor[idx] = excl; }
  if (idx == NN - 1) indptr[NN] = excl + d;
}

__global__ void k_fill(const int* __restrict__ row, const int* __restrict__ col,
                       const float* __restrict__ dinv, int* __restrict__ cursor,
                       int2* __restrict__ csw, float* __restrict__ rsum) {
  int e = blockIdx.x * blockDim.x + threadIdx.x;
  if (e >= NTOT) return;
  int r, c;
  if (e < NE) { r = row[e]; c = col[e]; } else { r = c = e - NE; }
  float wv = dinv[r] * dinv[c];
  int pos = atomicAdd(&cursor[c], 1);
  int2 m; m.x = r; m.y = __builtin_bit_cast(int, wv);
  csw[pos] = m;
  atomicAdd(&rsum[c], wv);
}

// ------------------------------------------------------------------
// Weight transposes into MFMA FRAGMENT layout
// ------------------------------------------------------------------
__device__ __forceinline__ size_t fragoff(int n, int k, int kb) {
  return ((size_t)(n >> 4) * kb + (k >> 5)) * 512 + ((k >> 3) & 3) * 128 + (n & 15) * 8;
}

__global__ void k_wconv3(const float* __restrict__ W0, const float* __restrict__ W3,
                         const float* __restrict__ W4,
                         _Float16* __restrict__ T0, _Float16* __restrict__ T3,
                         _Float16* __restrict__ T4) {
  int c = blockIdx.x * blockDim.x + threadIdx.x;   // 16B chunk index
  _Float16 ov[8];
  if (c < 4096) {                                  // W1: N=1024, Kp=32 (K=29)
    int n = c >> 2, k = (c & 3) * 8;
    #pragma unroll
    for (int i = 0; i < 8; ++i)
      ov[i] = (_Float16)((k + i < 29) ? W0[(size_t)(k + i) * 1024 + n] : 0.f);
    *(uint4*)&T0[fragoff(n, k, 1)] = *(const uint4*)ov;
  } else if (c < 4096 + 16384) {                   // W4: N=512, K=256
    int c2 = c - 4096;
    int n = c2 >> 5, k = (c2 & 31) * 8;
    #pragma unroll
    for (int i = 0; i < 8; ++i)
      ov[i] = (_Float16)W3[(size_t)(k + i) * 512 + n];
    *(uint4*)&T3[fragoff(n, k, 8)] = *(const uint4*)ov;
  } else if (c < 4096 + 16384 + 65536) {           // W5: N=1024, K=512
    int c3 = c - 20480;
    int n = c3 >> 6, k = (c3 & 63) * 8;
    #pragma unroll
    for (int i = 0; i < 8; ++i)
      ov[i] = (_Float16)W4[(size_t)(k + i) * 1024 + n];
    *(uint4*)&T4[fragoff(n, k, 16)] = *(const uint4*)ov;
  }
}

// W' = diag(sc) W -> fragment layout fp16; c[n] = sum_k sh_k W[k,n]
__global__ __launch_bounds__(256) void k_wfold(const float* __restrict__ W, int K, int N,
                                               const float* __restrict__ sums,
                                               const float* __restrict__ gamma,
                                               const float* __restrict__ beta,
                                               _Float16* __restrict__ T,
                                               float* __restrict__ c) {
  __shared__ float red[256];
  int n = blockIdx.x, tid = threadIdx.x;
  int kb = K >> 5;
  const float inv_n = 1.f / NN;
  float csum = 0.f;
  for (int kc = tid; kc < (K >> 3); kc += 256) {
    int k = kc * 8;
    _Float16 ov[8];
    #pragma unroll
    for (int i = 0; i < 8; ++i) {
      int ki = k + i;
      float mean = sums[ki] * inv_n;
      float var  = sums[K + ki] * inv_n - mean * mean;
      float sc   = gamma[ki] * rsqrtf(var + EPS_BN);
      float sh   = beta[ki] - mean * sc;
      float wv   = W[(size_t)ki * N + n];
      ov[i] = (_Float16)(sc * wv);
      csum += sh * wv;
    }
    *(uint4*)&T[fragoff(n, k, kb)] = *(const uint4*)ov;
  }
  red[tid] = csum;
  __syncthreads();
  for (int o = 128; o > 0; o >>= 1) {
    if (tid < o) red[tid] += red[tid + o];
    __syncthreads();
  }
  if (tid == 0) c[n] = red[0];
}

// ------------------------------------------------------------------
// L1 aggregation: fp32 x (F=29) -> fp16 out (stride 32).
// ------------------------------------------------------------------
#define AGG_CH 128
__global__ __launch_bounds__(128) void k_agg29(
    const float* __restrict__ X,
    const int* __restrict__ indptr, const int2* __restrict__ csw,
    _Float16* __restrict__ Y) {
  __shared__ int   s_src[AGG_CH];
  __shared__ float s_w[AGG_CH];
  __shared__ float red[128];
  int node = blockIdx.x;
  int tid  = threadIdx.x;
  int sub  = tid / 29;
  int feat = tid - sub * 29;
  bool act = tid < 116;
  int beg = indptr[node], end = indptr[node + 1];
  float acc = 0.f;
  for (int e0 = beg; e0 < end; e0 += AGG_CH) {
    int c = min(AGG_CH, end - e0);
    if (tid < c) {
      int2 m = csw[e0 + tid];
      s_src[tid] = m.x;
      s_w[tid]   = __builtin_bit_cast(float, m.y);
    }
    __syncthreads();
    if (act) {
      for (int j = 0; j < c; j += 4) {
        int jj = j + sub;
        if (jj < c) acc += s_w[jj] * X[(size_t)s_src[jj] * 29 + feat];
      }
    }
    __syncthreads();
  }
  red[tid] = acc;
  __syncthreads();
  if (tid < 32) {
    float v = 0.f;
    if (tid < 29) v = red[tid] + red[29 + tid] + red[58 + tid] + red[87 + tid];
    Y[(size_t)node * 32 + tid] = (_Float16)v;
  }
}

// ------------------------------------------------------------------
// Whole-row fp16 gather aggregation F=512, wave-per-node (4 nodes/block).
// ------------------------------------------------------------------
template<int MODE>
__global__ __launch_bounds__(256) void k_aggv(
    const _Float16* __restrict__ X, _Float16* __restrict__ Y,
    const int* __restrict__ indptr, const int2* __restrict__ csw,
    const float* __restrict__ rowsum,
    const float* __restrict__ p0, const float* __restrict__ p1,
    const float* __restrict__ p2)
{
  constexpr int F = 512;
  int wave = threadIdx.x >> 6;
  int lane = threadIdx.x & 63;
  int node = blockIdx.x * 4 + wave;
  int beg = indptr[node], end = indptr[node + 1];
  float acc[8];
  #pragma unroll
  for (int i = 0; i < 8; ++i) acc[i] = 0.f;
  const unsigned* Xl = (const unsigned*)X + lane * 4;

  auto body = [&](int e) {
    int2 m = csw[e];
    float we = __builtin_bit_cast(float, m.y);
    uint4 d = *(const uint4*)(Xl + (size_t)m.x * (F / 2));
    unsigned uu[4] = {d.x, d.y, d.z, d.w};
    #pragma unroll
    for (int i = 0; i < 4; ++i) {
      half2v h = __builtin_bit_cast(half2v, uu[i]);
      acc[2 * i]     = fmaf(we, (float)h[0], acc[2 * i]);
      acc[2 * i + 1] = fmaf(we, (float)h[1], acc[2 * i + 1]);
    }
  };
  int e = beg;
  for (; e + 8 <= end; e += 8) {
    body(e); body(e + 1); body(e + 2); body(e + 3);
    body(e + 4); body(e + 5); body(e + 6); body(e + 7);
  }
  for (; e < end; ++e) body(e);

  float s_n = rowsum[node];
  size_t ob = (size_t)node * F + lane * 8;
  _Float16 outv[8];
  #pragma unroll
  for (int i = 0; i < 8; ++i) {
    int f = lane * 8 + i;
    float v;
    if constexpr (MODE == 0) {
      v = fmaxf(acc[i] + s_n * p0[f] + p1[f], 0.f);
    } else {
      const float inv_n = 1.f / NN;
      float mean = p0[f] * inv_n;
      float var  = p0[F + f] * inv_n - mean * mean;
      float sc   = p1[f] * rsqrtf(var + EPS_BN);
      float sh   = p2[f] - mean * sc;
      v = sc * acc[i] + s_n * sh;
    }
    outv[i] = (_Float16)v;
  }
  *(uint4*)(Y + ob) = *(const uint4*)outv;
}

// ------------------------------------------------------------------
// Paired-node fp16 gather aggregation F=256 (2 nodes/wave, 16B loads).
// ------------------------------------------------------------------
template<int MODE>
__global__ __launch_bounds__(256) void k_aggp(
    const _Float16* __restrict__ X, _Float16* __restrict__ Y,
    const int* __restrict__ indptr, const int2* __restrict__ csw,
    const float* __restrict__ rowsum,
    const float* __restrict__ p0, const float* __restrict__ p1,
    const float* __restrict__ p2)
{
  constexpr int F = 256;
  int wave = threadIdx.x >> 6;
  int lane = threadIdx.x & 63;
  int half = lane >> 5;
  int l32  = lane & 31;
  int node = blockIdx.x * 8 + wave * 2 + half;
  int beg = indptr[node], end = indptr[node + 1];
  int len = end - beg;
  int len0 = __shfl(len, 0, 64);
  int len1 = __shfl(len, 32, 64);
  int maxlen = max(len0, len1);

  float acc[8];
  #pragma unroll
  for (int i = 0; i < 8; ++i) acc[i] = 0.f;
  const unsigned* Xl = (const unsigned*)X + l32 * 4;

  auto body = [&](int t) {
    int e = beg + min(t, len - 1);
    int2 m = csw[e];
    float we = (t < len) ? __builtin_bit_cast(float, m.y) : 0.f;
    uint4 d = *(const uint4*)(Xl + (size_t)m.x * (F / 2));
    unsigned uu[4] = {d.x, d.y, d.z, d.w};
    #pragma unroll
    for (int i = 0; i < 4; ++i) {
      half2v h = __builtin_bit_cast(half2v, uu[i]);
      acc[2 * i]     = fmaf(we, (float)h[0], acc[2 * i]);
      acc[2 * i + 1] = fmaf(we, (float)h[1], acc[2 * i + 1]);
    }
  };
  int t = 0;
  for (; t + 4 <= maxlen; t += 4) { body(t); body(t + 1); body(t + 2); body(t + 3); }
  for (; t < maxlen; ++t) body(t);

  float s_n = rowsum[node];
  size_t ob = (size_t)node * F + l32 * 8;
  _Float16 outv[8];
  #pragma unroll
  for (int i = 0; i < 8; ++i) {
    int f = l32 * 8 + i;
    float v;
    if constexpr (MODE == 0) {
      v = fmaxf(acc[i] + s_n * p0[f] + p1[f], 0.f);
    } else {
      const float inv_n = 1.f / NN;
      float mean = p0[f] * inv_n;
      float var  = p0[F + f] * inv_n - mean * mean;
      float sc   = p1[f] * rsqrtf(var + EPS_BN);
      float sh   = p2[f] - mean * sc;
      v = sc * acc[i] + s_n * sh;
    }
    outv[i] = (_Float16)v;
  }
  *(uint4*)(Y + ob) = *(const uint4*)outv;
}

// ------------------------------------------------------------------
// fp16 MFMA GEMM: A async-staged in LDS (XOR swizzle); B read directly
// from global in FRAGMENT layout. LDS-coalesced fp16 C epilogue.
// ------------------------------------------------------------------
template<int BK>
__global__ __launch_bounds__(256) void k_gemm16(
    const _Float16* __restrict__ A, const _Float16* __restrict__ Bf,
    const float* __restrict__ bias,
    _Float16* __restrict__ Ch,
    float* __restrict__ stats,
    int N, int K, int do_relu, int nbx)
{
  __shared__ __align__(16) union UU {
    _Float16 a[128 * BK];
    _Float16 c[128 * 136];
  } u;
  __shared__ float sred[256];

  const int tid  = threadIdx.x;
  const int wave = tid >> 6;
  const int lane = tid & 63;

  int lin = blockIdx.x;
  int xcd = lin & 7, seq = lin >> 3;
  int bx = seq % nbx, grp = seq / nbx;
  int by = xcd + 8 * grp;            // 0..159
  const int row0 = by * 128;
  const int col0 = bx * 128;

  const int q  = lane >> 4;
  const int mm = lane & 15;
  const int wm = wave >> 1;
  const int wn = wave & 1;

  sred[tid] = 0.f;

  constexpr int NREP = (BK == 32) ? 2 : 4;
  constexpr int RPW  = (BK == 32) ? 16 : 8;
  const _Float16* pA[NREP];
  _Float16* dstA[NREP];
  {
    int rl = (BK == 32) ? (lane >> 2) : (lane >> 3);
    int cp = (BK == 32) ? (lane & 3) : (lane & 7);
    #pragma unroll
    for (int rep = 0; rep < NREP; ++rep) {
      int trow = wave * 32 + rep * RPW;
      int s = (BK == 32) ? ((lane >> 3) & 3) : ((rep & 1) * 4 + (rl >> 1));
      int csrc = cp ^ s;
      pA[rep] = A + (size_t)(row0 + trow + rl) * K + csrc * 8;
      dstA[rep] = u.a + trow * BK;
    }
  }

  const int sR = (BK == 32) ? ((mm >> 1) & 3) : (mm >> 1);
  int rdA[4];
  #pragma unroll
  for (int i = 0; i < 4; ++i) rdA[i] = (wm * 64 + i * 16 + mm) * BK;

  const int kb = K >> 5;
  const _Float16* pb[4];
  #pragma unroll
  for (int j = 0; j < 4; ++j)
    pb[j] = Bf + (size_t)((col0 + wn * 64 + j * 16) >> 4) * kb * 512 + lane * 8;

  floatx4 acc[4][4];
  #pragma unroll
  for (int i = 0; i < 4; ++i)
    #pragma unroll
    for (int j = 0; j < 4; ++j) acc[i][j] = floatx4{0.f, 0.f, 0.f, 0.f};

  for (int k0 = 0; k0 < K; k0 += BK) {
    #pragma unroll
    for (int rep = 0; rep < NREP; ++rep) {
      gload_lds16(pA[rep], dstA[rep]);
      pA[rep] += BK;
    }
    __syncthreads();

    #pragma unroll
    for (int kk = 0; kk < BK / 32; ++kk) {
      half8 bv[4];
      #pragma unroll
      for (int j = 0; j < 4; ++j) { bv[j] = *(const half8*)pb[j]; pb[j] += 512; }
      int pos = ((q + 4 * kk) ^ sR) * 8;
      half8 av[4];
      #pragma unroll
      for (int i = 0; i < 4; ++i) av[i] = *(const half8*)&u.a[rdA[i] + pos];
      #pragma unroll
      for (int j = 0; j < 4; ++j)
        #pragma unroll
        for (int i = 0; i < 4; ++i)
          acc[i][j] = __builtin_amdgcn_mfma_f32_16x16x32_f16(av[i], bv[j], acc[i][j], 0, 0, 0);
    }
    __syncthreads();
  }

  float sloc[4]  = {0.f, 0.f, 0.f, 0.f};
  float s2loc[4] = {0.f, 0.f, 0.f, 0.f};
  #pragma unroll
  for (int j = 0; j < 4; ++j) {
    int cl = wn * 64 + j * 16 + mm;
    float bv = bias ? bias[col0 + cl] : 0.f;
    #pragma unroll
    for (int i = 0; i < 4; ++i) {
      #pragma unroll
      for (int r = 0; r < 4; ++r) {
        int rl = wm * 64 + i * 16 + q * 4 + r;
        float v = acc[i][j][r] + bv;
        if (do_relu) v = fmaxf(v, 0.f);
        u.c[rl * 136 + cl] = (_Float16)v;
        if (row0 + rl < NN) { sloc[j] += v; s2loc[j] += v * v; }
      }
    }
  }

  if (stats) {
    #pragma unroll
    for (int j = 0; j < 4; ++j) {
      float a = sloc[j], b2 = s2loc[j];
      a  += __shfl_xor(a, 16, 64);  a  += __shfl_xor(a, 32, 64);
      b2 += __shfl_xor(b2, 16, 64); b2 += __shfl_xor(b2, 32, 64);
      if (q == 0) {
        int cl = wn * 64 + j * 16 + mm;
        atomicAdd(&sred[cl], a);
        atomicAdd(&sred[128 + cl], b2);
      }
    }
  }
  __syncthreads();

  #pragma unroll
  for (int pass = 0; pass < 8; ++pass) {
    int cidx = tid + pass * 256;
    int r = cidx >> 4, kc = cidx & 15;
    int rr = row0 + r;
    if (rr < NN) {
      uint4 d = *(const uint4*)&u.c[r * 136 + kc * 8];
      *(uint4*)&Ch[(size_t)rr * N + col0 + kc * 8] = d;
    }
  }

  if (stats && tid < 128) {
    atomicAdd(&stats[col0 + tid], sred[tid]);
    atomicAdd(&stats[N + col0 + tid], sred[128 + tid]);
  }
}

// ------------------------------------------------------------------
// Slim BN stats over fp16 tensor (stride == F)
// ------------------------------------------------------------------
__global__ __launch_bounds__(256) void k_stats16(const _Float16* __restrict__ X, int F,
                                                 float* __restrict__ sums) {
  int tid = threadIdx.x;
  int npf = F >> 8;
  float s[2] = {0.f, 0.f}, s2[2] = {0.f, 0.f};
  for (int r = blockIdx.x; r < NN; r += gridDim.x) {
    #pragma unroll
    for (int i = 0; i < 2; ++i) {
      if (i < npf) {
        float v = (float)X[(size_t)r * F + tid + i * 256];
        s[i] += v; s2[i] += v * v;
      }
    }
  }
  #pragma unroll
  for (int i = 0; i < 2; ++i) {
    if (i < npf) {
      atomicAdd(&sums[tid + i * 256], s[i]);
      atomicAdd(&sums[F + tid + i * 256], s2[i]);
    }
  }
}

// ------------------------------------------------------------------
// Gate with inline BN5 fold
// ------------------------------------------------------------------
__global__ __launch_bounds__(256) void k_gate2(const _Float16* __restrict__ X,
                                               const float* __restrict__ sums,
                                               const float* __restrict__ g5,
                                               const float* __restrict__ be5,
                                               const float* __restrict__ Wg,
                                               const float* __restrict__ bg,
                                               float* __restrict__ gate) {
  __shared__ float red[512];
  int n = blockIdx.x, tid = threadIdx.x;
  int f = tid * 4;
  const float inv_n = 1.f / NN;
  uint2 u = *(const uint2*)(X + (size_t)n * 1024 + f);
  half2v h0 = __builtin_bit_cast(half2v, u.x);
  half2v h1 = __builtin_bit_cast(half2v, u.y);
  float xv[4] = {(float)h0[0], (float)h0[1], (float)h1[0], (float)h1[1]};
  float s = 0.f, t = 0.f;
  #pragma unroll
  for (int i = 0; i < 4; ++i) {
    int ff = f + i;
    float mean = sums[ff] * inv_n;
    float var  = sums[1024 + ff] * inv_n - mean * mean;
    float sc   = g5[ff] * rsqrtf(var + EPS_BN);
    float sh   = be5[ff] - mean * sc;
    float wg   = Wg[ff];
    s += xv[i] * (sc * wg);
    t += sh * wg;
  }
  red[tid] = s;
  red[256 + tid] = t;
  __syncthreads();
  for (int o = 128; o > 0; o >>= 1) {
    if (tid < o) { red[tid] += red[tid + o]; red[256 + tid] += red[256 + tid + o]; }
    __syncthreads();
  }
  if (tid == 0) gate[n] = red[0] + red[256] + bg[0];
}

// ------------------------------------------------------------------
// Fused segred + pool (BN5 fold, unroll-4 node loop) + MLP head
// ------------------------------------------------------------------
__global__ __launch_bounds__(256) void k_poolhead(
    const _Float16* __restrict__ X, const float* __restrict__ gate,
    const int* __restrict__ goff,
    const float* __restrict__ sums, const float* __restrict__ g5,
    const float* __restrict__ be5,
    const float* __restrict__ Wf2, const float* __restrict__ bf2,
    const float* __restrict__ Wf3, const float* __restrict__ bf3,
    const float* __restrict__ Wf4, const float* __restrict__ bf4,
    float* __restrict__ out)
{
  __shared__ float red[256];
  __shared__ float sp[1024];
  __shared__ float sp2[128];
  __shared__ float sp3[16];
  int g = blockIdx.x, tid = threadIdx.x;
  int beg = goff[g], end = goff[g + 1];
  bool nonempty = end > beg;

  // segred: max
  float m = -3.4e38f;
  for (int n = beg + tid; n < end; n += 256) m = fmaxf(m, gate[n]);
  red[tid] = m;
  __syncthreads();
  for (int o = 128; o > 0; o >>= 1) {
    if (tid < o) red[tid] = fmaxf(red[tid], red[tid + o]);
    __syncthreads();
  }
  m = red[0];
  __syncthreads();
  // segred: sum of exp
  float s = 0.f;
  for (int n = beg + tid; n < end; n += 256) s += expf(gate[n] - m);
  red[tid] = s;
  __syncthreads();
  for (int o = 128; o > 0; o >>= 1) {
    if (tid < o) red[tid] += red[tid + o];
    __syncthreads();
  }
  float inv = nonempty ? (1.f / red[0]) : 0.f;

  // pool with BN5 fold -> LDS; node loop unrolled x4 for memory parallelism
  int f = tid * 4;
  const float inv_n = 1.f / NN;
  float acc[4] = {0.f, 0.f, 0.f, 0.f};
  if (nonempty) {
    const _Float16* Xf = X + f;
    int n = beg;
    for (; n + 4 <= end; n += 4) {
      float a0 = expf(gate[n]     - m);
      float a1 = expf(gate[n + 1] - m);
      float a2 = expf(gate[n + 2] - m);
      float a3 = expf(gate[n + 3] - m);
      uint2 u0 = *(const uint2*)(Xf + (size_t)(n)     * 1024);
      uint2 u1 = *(const uint2*)(Xf + (size_t)(n + 1) * 1024);
      uint2 u2 = *(const uint2*)(Xf + (size_t)(n + 2) * 1024);
      uint2 u3 = *(const uint2*)(Xf + (size_t)(n + 3) * 1024);
      half2v p00 = __builtin_bit_cast(half2v, u0.x), p01 = __builtin_bit_cast(half2v, u0.y);
      half2v p10 = __builtin_bit_cast(half2v, u1.x), p11 = __builtin_bit_cast(half2v, u1.y);
      half2v p20 = __builtin_bit_cast(half2v, u2.x), p21 = __builtin_bit_cast(half2v, u2.y);
      half2v p30 = __builtin_bit_cast(half2v, u3.x), p31 = __builtin_bit_cast(half2v, u3.y);
      acc[0] += a0 * (float)p00[0] + a1 * (float)p10[0] + a2 * (float)p20[0] + a3 * (float)p30[0];
      acc[1] += a0 * (float)p00[1] + a1 * (float)p10[1] + a2 * (float)p20[1] + a3 * (float)p30[1];
      acc[2] += a0 * (float)p01[0] + a1 * (float)p11[0] + a2 * (float)p21[0] + a3 * (float)p31[0];
      acc[3] += a0 * (float)p01[1] + a1 * (float)p11[1] + a2 * (float)p21[1] + a3 * (float)p31[1];
    }
    for (; n < end; ++n) {
      float a = expf(gate[n] - m);
      uint2 u0 = *(const uint2*)(Xf + (size_t)n * 1024);
      half2v p0 = __builtin_bit_cast(half2v, u0.x), p1 = __builtin_bit_cast(half2v, u0.y);
      acc[0] += a * (float)p0[0];
      acc[1] += a * (float)p0[1];
      acc[2] += a * (float)p1[0];
      acc[3] += a * (float)p1[1];
    }
  }
  #pragma unroll
  for (int i = 0; i < 4; ++i) {
    int ff = f + i;
    float mean = sums[ff] * inv_n;
    float var  = sums[1024 + ff] * inv_n - mean * mean;
    float sc   = g5[ff] * rsqrtf(var + EPS_BN);
    float sh   = be5[ff] - mean * sc;
    sp[ff] = nonempty ? (acc[i] * inv * sc + sh) : 0.f;
  }
  __syncthreads();

  // head
  if (tid < 128) {
    float s2 = bf2[tid];
    for (int k = 0; k < 1024; ++k) s2 += sp[k] * Wf2[k * 128 + tid];
    sp2[tid] = fmaxf(s2, 0.f);
  }
  __syncthreads();
  if (tid < 16) {
    float t = bf3[tid];
    for (int k = 0; k < 128; ++k) t += sp2[k] * Wf3[k * 16 + tid];
    sp3[tid] = fmaxf(t, 0.f);
  }
  __syncthreads();
  if (tid == 0) {
    float t = bf4[0];
    for (int k = 0; k < 16; ++k) t += sp3[k] * Wf4[k];
    out[g] = t;
  }
}

// ------------------------------------------------------------------
extern "C" void kernel_launch(void* const* d_in, const int* in_sizes, int n_in,
                              void* d_out, int out_size, void* d_ws, size_t ws_size,
                              hipStream_t stream) {
  const float* x     = (const float*)d_in[0];
  const int*   ei    = (const int*)d_in[1];
  const int*   batch = (const int*)d_in[2];
  const float* W[5]; const float* b[5]; const float* g[5]; const float* be[5];
  for (int l = 0; l < 5; ++l) {
    W[l]  = (const float*)d_in[3 + 4 * l];
    b[l]  = (const float*)d_in[4 + 4 * l];
    g[l]  = (const float*)d_in[5 + 4 * l];
    be[l] = (const float*)d_in[6 + 4 * l];
  }
  const float* Wg  = (const float*)d_in[23];
  const float* bg  = (const float*)d_in[24];
  const float* Wf2 = (const float*)d_in[25];
  const float* bf2 = (const float*)d_in[26];
  const float* Wf3 = (const float*)d_in[27];
  const float* bf3 = (const float*)d_in[28];
  const float* Wf4 = (const float*)d_in[29];
  const float* bf4 = (const float*)d_in[30];
  float* out = (float*)d_out;

  const int* row = ei;
  const int* col = ei + NE;

  char* base = (char*)d_ws;
  size_t off = 0;
  auto alloc = [&](size_t bytes) -> char* {
    char* p = base + off;
    off = (off + bytes + 255) & ~(size_t)255;
    return p;
  };
  _Float16*  AH  = (_Float16*)alloc((size_t)MPAD * 1024 * 2);
  _Float16*  ASM = (_Float16*)alloc((size_t)MPAD * 32 * 2);
  _Float16*  BF  = (_Float16*)alloc((size_t)NN * 512 * 2);
  _Float16*  BF2 = (_Float16*)alloc((size_t)NN * 512 * 2);
  _Float16*  H5  = (_Float16*)alloc((size_t)NN * 1024 * 2);
  const int wtsz[5] = {1024 * 32, 512 * 1024, 256 * 512, 512 * 256, 1024 * 512};
  _Float16* WT[5];
  for (int l = 0; l < 5; ++l) WT[l] = (_Float16*)alloc((size_t)wtsz[l] * 2);
  float* c2  = (float*)alloc(512 * 4);
  float* c3  = (float*)alloc(256 * 4);
  float* dinv    = (float*)alloc(NN * 4);
  int*   indptr  = (int*)alloc((NN + 1) * 4);
  int*   cursor  = (int*)alloc(NN * 4);
  int2*  csw     = (int2*)alloc((size_t)NTOT * 8);
  int*   psum    = (int*)alloc((NBLK + 1) * 4);
  int*   pbase   = (int*)alloc((NBLK + 1) * 4);
  int*   goff    = (int*)alloc((NG + 1) * 4);
  float* gate    = (float*)alloc(NN * 4);
  size_t znf = 6656 + NN + NG + NN;
  float* zbase = (float*)alloc(znf * 4);
  float* bns  = zbase;
  int*   deg  = (int*)(zbase + 6656);
  int*   gcnt = (int*)(zbase + 6656 + NN);
  float* rsum = zbase + 6656 + NN + NG;
  float* bns1 = bns;          // F=1024
  float* bns2 = bns + 2048;   // F=512
  float* bns3 = bns + 3072;   // F=256
  float* bns4 = bns + 3584;   // F=512
  float* bns5 = bns + 4608;   // F=1024

  // ---- preprocessing ----
  hipMemsetAsync(zbase, 0, znf * 4, stream);
  k_deg<<<(NTOT + 255) / 256, 256, 0, stream>>>(col, deg, batch, gcnt);
  k_pre1<<<NBLK, 256, 0, stream>>>(deg, dinv, psum);
  k_pre2<<<1, 256, 0, stream>>>(psum, pbase, gcnt, goff);
  k_pre3<<<NBLK, 256, 0, stream>>>(deg, pbase, indptr, cursor);
  k_fill<<<(NTOT + 255) / 256, 256, 0, stream>>>(row, col, dinv, cursor, csw, rsum);
  k_wconv3<<<336, 256, 0, stream>>>(W[0], W[3], W[4], WT[0], WT[3], WT[4]);

  auto gemm = [&](const _Float16* Aop, int wl, const float* bias,
                  _Float16* Ch, float* stats, int Nn, int Kk, int relu) {
    int nbx = Nn / 128;
    if (Kk == 32)
      k_gemm16<32><<<nbx * 160, 256, 0, stream>>>(Aop, WT[wl], bias, Ch, stats, Nn, Kk, relu, nbx);
    else
      k_gemm16<64><<<nbx * 160, 256, 0, stream>>>(Aop, WT[wl], bias, Ch, stats, Nn, Kk, relu, nbx);
  };

  // ---- layer 1 (29 -> 1024): agg-first; GEMM1 fuses bias/relu/stats ----
  k_agg29<<<NN, 128, 0, stream>>>(x, indptr, csw, ASM);
  gemm(ASM, 0, b[0], AH, bns1, 1024, 32, 1);                     // r1 fp16

  // ---- layer 2 (1024 -> 512): BN1 folded into W2; transform-first ----
  k_wfold<<<512, 256, 0, stream>>>(W[1], 1024, 512, bns1, g[0], be[0], WT[1], c2);
  gemm(AH, 1, nullptr, BF, nullptr, 512, 1024, 0);               // G2
  k_aggv<0><<<NN / 4, 256, 0, stream>>>(BF, AH, indptr, csw, rsum, c2, b[1], nullptr); // r2
  k_stats16<<<512, 256, 0, stream>>>(AH, 512, bns2);

  // ---- layer 3 (512 -> 256): BN2 folded into W3; transform-first ----
  k_wfold<<<256, 256, 0, stream>>>(W[2], 512, 256, bns2, g[1], be[1], WT[2], c3);
  gemm(AH, 2, nullptr, BF2, nullptr, 256, 512, 0);               // G3
  k_aggp<0><<<NN / 8, 256, 0, stream>>>(BF2, BF, indptr, csw, rsum, c3, b[2], nullptr); // r3
  k_stats16<<<512, 256, 0, stream>>>(BF, 256, bns3);

  // ---- layer 4 (256 -> 512): agg-first, BN3 inline in agg epilogue ----
  k_aggp<1><<<NN / 8, 256, 0, stream>>>(BF, AH, indptr, csw, rsum, bns3, g[2], be[2]); // a4
  gemm(AH, 3, b[3], BF2, bns4, 512, 256, 1);                     // r4 fp16 + stats

  // ---- layer 5 (512 -> 1024): agg-first, BN4 inline; GEMM5 fp16 out ----
  k_aggv<1><<<NN / 4, 256, 0, stream>>>(BF2, AH, indptr, csw, rsum, bns4, g[3], be[3]); // a5
  gemm(AH, 4, b[4], H5, bns5, 1024, 512, 1);                     // r5 fp16 + stats

  // ---- attention pooling (inline BN5 fold) + head ----
  k_gate2<<<NN, 256, 0, stream>>>(H5, bns5, g[4], be[4], Wg, bg, gate);
  k_poolhead<<<NG, 256, 0, stream>>>(H5, gate, goff, bns5, g[4], be[4],
                                     Wf2, bf2, Wf3, bf3, Wf4, bf4, out);
}